// Round 4
// baseline (566.422 us; speedup 1.0000x reference)
//
#include <hip/hip_runtime.h>

// ============================================================================
// XModel_66795331387584: complex phase-feature ridge loss on MI355X (gfx950)
//
// loss = mean_{a,z} sum_d | num_MN/den_MN - num_X/den_X |^2
// den path: split-bf16 (hi+lo), fp32 out (tail-dominated 1/|den|^2).
// gamma_X via 1-term Neumann: gx = (K12 - K@K12/reg)/reg (rel err 4e-6).
//
// R10: num GEMM on MX-fp8 (mfma_scale 16x16x128, uniform E8M0 scales).
// R11: T1 XCD-chunked work map + T2 LDS XOR swizzle + T5 setprio in k_mm /
//      k_big GEMM. k_mm: 153->118us (93% of mixed MFMA pipe roofline).
// R12 LESSON: __launch_bounds__(256,3) VGPR cap 84 < 128-reg acc -> spill.
// R13 LESSON: k_redprep 2000-block regrid LOST ~23us: 2000 same-address
//      atomics serialize at one L2 line + 16B loads killed per-thread ILP.
// R14: (a) k_redprep 1000 blocks (1 a-row/block, 8-wide loads, 1000 atomics);
//      (b) k_mm split into 2 phase dispatches (0: MN num planes + MN den;
//      1: X num planes + X den) — same work/locality, makes the four hidden
//      kernels visible in top-5 profiling.
// ============================================================================

typedef __bf16 bf16;
typedef __bf16 bf16x8 __attribute__((ext_vector_type(8)));
typedef float f32x4 __attribute__((ext_vector_type(4)));
typedef int i32x8 __attribute__((ext_vector_type(8)));
typedef int i32x4 __attribute__((ext_vector_type(4)));

#define AS1 __attribute__((address_space(1)))
#define AS3 __attribute__((address_space(3)))

__device__ __forceinline__ void async16(const void* g, void* l) {
  __builtin_amdgcn_global_load_lds((AS1 const unsigned int*)g,
                                   (AS3 unsigned int*)l, 16, 0, 0);
}

__device__ __forceinline__ unsigned int pk4f8(float a, float b, float c,
                                              float d) {
  int w = __builtin_amdgcn_cvt_pk_fp8_f32(a, b, 0, false);
  w = __builtin_amdgcn_cvt_pk_fp8_f32(c, d, w, true);
  return (unsigned int)w;
}

// 32-B fragment read from a 128-B-row LDS tile with 16-B-chunk XOR swizzle.
__device__ __forceinline__ i32x8 ld_swz32(const unsigned char* rowp, int kg,
                                          int fsw) {
  i32x4 lo = *(const i32x4*)(rowp + (kg ^ fsw));
  i32x4 hi = *(const i32x4*)(rowp + ((kg + 16) ^ fsw));
  i32x8 v;
  v[0] = lo[0]; v[1] = lo[1]; v[2] = lo[2]; v[3] = lo[3];
  v[4] = hi[0]; v[5] = hi[1]; v[6] = hi[2]; v[7] = hi[3];
  return v;
}

// -------- B-plane builders (fp8, 64x64 tile) --------------------------------
// planes 0..7: 64 * M_d * gMN^T ; planes 8..15: 8192 * X_d * gx
__device__ __forceinline__ void build_mn(const float* __restrict__ gMN,
                                         const float* __restrict__ Mm,
                                         unsigned char* __restrict__ B8,
                                         int j0, int zl0, int zg0, int ZC,
                                         int tid, float (*t)[65]) {
  const size_t PL = (size_t)ZC * 2048;
  int zg = zg0 + zl0;
  for (int e = tid; e < 4096; e += 256) {
    int r = e >> 6, c = e & 63;
    t[r][c] = (j0 + r < 2000 && zg + c < 2000)
                  ? gMN[(size_t)(j0 + r) * 2000 + zg + c] : 0.f;
  }
  __syncthreads();
  const float4* M4 = (const float4*)Mm;
#pragma unroll
  for (int it = 0; it < 2; ++it) {
    int idx = it * 256 + tid;
    int zr = idx >> 3, c8 = (idx & 7) * 8;
    float g[8], mrow[8][8];
#pragma unroll
    for (int e = 0; e < 8; ++e) {
      g[e] = 64.f * t[c8 + e][zr];
      int jj = j0 + c8 + e;
      if (jj < 2000) {
        float4 ma = M4[jj * 2], mb = M4[jj * 2 + 1];
        mrow[e][0] = ma.x; mrow[e][1] = ma.y; mrow[e][2] = ma.z;
        mrow[e][3] = ma.w; mrow[e][4] = mb.x; mrow[e][5] = mb.y;
        mrow[e][6] = mb.z; mrow[e][7] = mb.w;
      } else {
#pragma unroll
        for (int d = 0; d < 8; ++d) mrow[e][d] = 0.f;
      }
    }
    size_t ob = (size_t)(zl0 + zr) * 2048 + j0 + c8;
#pragma unroll
    for (int d = 0; d < 8; ++d) {
      uint2 u;
      u.x = pk4f8(g[0] * mrow[0][d], g[1] * mrow[1][d], g[2] * mrow[2][d],
                  g[3] * mrow[3][d]);
      u.y = pk4f8(g[4] * mrow[4][d], g[5] * mrow[5][d], g[6] * mrow[6][d],
                  g[7] * mrow[7][d]);
      *(uint2*)(B8 + (size_t)d * PL + ob) = u;
    }
  }
}

__device__ __forceinline__ void build_x(const bf16* __restrict__ gxHi,
                                        const bf16* __restrict__ gxLo,
                                        const float* __restrict__ Xm,
                                        unsigned char* __restrict__ B8,
                                        int j0, int zl0, int zg0, int ZC,
                                        int tid) {
  const size_t PL = (size_t)ZC * 2048;
  const float4* X4 = (const float4*)Xm;
#pragma unroll
  for (int it = 0; it < 2; ++it) {
    int idx = it * 256 + tid;
    int zr = idx >> 3, c8 = (idx & 7) * 8;
    size_t gb = (size_t)(zg0 + zl0 + zr) * 2048 + j0 + c8;
    bf16x8 vh = *(const bf16x8*)(gxHi + gb);
    bf16x8 vl = *(const bf16x8*)(gxLo + gb);
    float gx[8], xr[8][8];
#pragma unroll
    for (int e = 0; e < 8; ++e) {
      gx[e] = 8192.f * ((float)vh[e] + (float)vl[e]);
      int jj = j0 + c8 + e;
      if (jj < 2000) {
        float4 xa = X4[jj * 2], xb = X4[jj * 2 + 1];
        xr[e][0] = xa.x; xr[e][1] = xa.y; xr[e][2] = xa.z; xr[e][3] = xa.w;
        xr[e][4] = xb.x; xr[e][5] = xb.y; xr[e][6] = xb.z; xr[e][7] = xb.w;
      } else {
#pragma unroll
        for (int d = 0; d < 8; ++d) xr[e][d] = 0.f;
      }
    }
    size_t ob = (size_t)(zl0 + zr) * 2048 + j0 + c8;
#pragma unroll
    for (int d = 0; d < 8; ++d) {
      uint2 u;
      u.x = pk4f8(gx[0] * xr[0][d], gx[1] * xr[1][d], gx[2] * xr[2][d],
                  gx[3] * xr[3][d]);
      u.y = pk4f8(gx[4] * xr[4][d], gx[5] * xr[5][d], gx[6] * xr[6][d],
                  gx[7] * xr[7][d]);
      *(uint2*)(B8 + (size_t)(8 + d) * PL + ob) = u;
    }
  }
}

// ---------------- k_cvt: converts + gN planes + out zero --------------------
__global__ __launch_bounds__(256) void k_cvt(
    const float* __restrict__ K11, const float* __restrict__ K12,
    const float* __restrict__ gN, bf16* __restrict__ Kbf,
    bf16* __restrict__ K12T, bf16* __restrict__ K12TL,
    bf16* __restrict__ BtNh, bf16* __restrict__ BtNl,
    float* __restrict__ out) {
  __shared__ float t[64][65];
  const int bid = blockIdx.x, tid = threadIdx.x;
  if (bid < 2048) {
    if (bid == 0 && tid == 0) out[0] = 0.f;
    int e = (bid * 256 + tid) * 8;
    int j = e >> 11, k = e & 2047;
    bf16x8 v;
    if (j < 2000 && k < 2000) {
      const float4* s = (const float4*)(K11 + (size_t)j * 2000 + k);
      float4 f0 = s[0], f1 = s[1];
      v[0] = (bf16)f0.x; v[1] = (bf16)f0.y; v[2] = (bf16)f0.z; v[3] = (bf16)f0.w;
      v[4] = (bf16)f1.x; v[5] = (bf16)f1.y; v[6] = (bf16)f1.z; v[7] = (bf16)f1.w;
    } else {
      for (int i = 0; i < 8; ++i) v[i] = (bf16)0.f;
    }
    *(bf16x8*)(Kbf + e) = v;
  } else {
    bool isK12 = bid < 3072;
    const float* src = isK12 ? K12 : gN;
    bf16* dh = isK12 ? K12T : BtNh;
    bf16* dl = isK12 ? K12TL : BtNl;
    int b2 = bid - (isK12 ? 2048 : 3072);
    int j0 = (b2 & 31) * 64, z0 = (b2 >> 5) * 64;
    for (int e = tid; e < 4096; e += 256) {
      int r = e >> 6, c = e & 63;
      t[r][c] = (j0 + r < 2000 && z0 + c < 2000)
                    ? src[(size_t)(j0 + r) * 2000 + z0 + c] : 0.f;
    }
    __syncthreads();
#pragma unroll
    for (int it = 0; it < 2; ++it) {
      int idx = it * 256 + tid;
      int zr = idx >> 3, c8 = (idx & 7) * 8;
      bf16x8 vh, vl;
#pragma unroll
      for (int e = 0; e < 8; ++e) {
        float g = t[c8 + e][zr];
        bf16 h = (bf16)g;
        vh[e] = h;
        vl[e] = (bf16)(g - (float)h);
      }
      size_t ob = (size_t)(z0 + zr) * 2048 + j0 + c8;
      *(bf16x8*)(dh + ob) = vh;
      *(bf16x8*)(dl + ob) = vl;
    }
  }
}

// --------- k_big: gemm1 tiles + phases (+fp8) + prepMN(chunk0) --------------
__global__ __launch_bounds__(256, 2) void k_big(
    const bf16* __restrict__ K12T, const bf16* __restrict__ K12TL,
    const bf16* __restrict__ Kbf, const float* __restrict__ ll,
    const float* __restrict__ al, const float* __restrict__ Nm,
    const float* __restrict__ Xm, const float* __restrict__ gMN,
    const float* __restrict__ Mm, bf16* __restrict__ gxHi,
    bf16* __restrict__ gxLo, bf16* __restrict__ AphH,
    bf16* __restrict__ AphL, unsigned char* __restrict__ Aph8,
    unsigned char* __restrict__ B8, int ZC) {
  __shared__ __align__(16) char smem[34816];
  const int tid = threadIdx.x;
  const int bid = blockIdx.x;
  if (bid >= 1280) {
    int pid = bid - 1280;
    build_mn(gMN, Mm, B8, (pid & 31) * 64, (pid >> 5) * 64, 0, ZC, tid,
             (float(*)[65])smem);
    return;
  }
  if (bid >= 256) {
    // ---- phases: a = bid-256, 8 j per thread
    const size_t PA = (size_t)1024 * 2048;
    int a = bid - 256;
    int j0 = tid * 8;
    float vc[4][8];
    if (a < 1000) {
      const float4* A4 = (const float4*)al;
      const float4* N4 = (const float4*)Nm;
      const float4* X4 = (const float4*)Xm;
      float4 a0 = A4[a * 2], a1 = A4[a * 2 + 1];
#pragma unroll
      for (int e = 0; e < 8; ++e) {
        int j = j0 + e;
        if (j < 2000) {
          float4 n0 = N4[j * 2], n1 = N4[j * 2 + 1];
          float4 x0 = X4[j * 2], x1 = X4[j * 2 + 1];
          float pn = a0.x * n0.x + a0.y * n0.y + a0.z * n0.z + a0.w * n0.w +
                     a1.x * n1.x + a1.y * n1.y + a1.z * n1.z + a1.w * n1.w;
          float px = a0.x * x0.x + a0.y * x0.y + a0.z * x0.z + a0.w * x0.w +
                     a1.x * x1.x + a1.y * x1.y + a1.z * x1.z + a1.w * x1.w;
          __sincosf(pn, &vc[1][e], &vc[0][e]);
          __sincosf(px, &vc[3][e], &vc[2][e]);
        } else {
          vc[0][e] = vc[1][e] = vc[2][e] = vc[3][e] = 0.f;
        }
      }
    } else {
#pragma unroll
      for (int p = 0; p < 4; ++p)
#pragma unroll
        for (int e = 0; e < 8; ++e) vc[p][e] = 0.f;
    }
    size_t o = (size_t)a * 2048 + j0;
#pragma unroll
    for (int p = 0; p < 4; ++p) {
      bf16x8 vh, vl;
#pragma unroll
      for (int e = 0; e < 8; ++e) {
        bf16 h = (bf16)vc[p][e];
        vh[e] = h;
        vl[e] = (bf16)(vc[p][e] - (float)h);
      }
      *(bf16x8*)(AphH + p * PA + o) = vh;
      *(bf16x8*)(AphL + p * PA + o) = vl;
      uint2 u8;
      u8.x = pk4f8(vc[p][0], vc[p][1], vc[p][2], vc[p][3]);
      u8.y = pk4f8(vc[p][4], vc[p][5], vc[p][6], vc[p][7]);
      *(uint2*)(Aph8 + p * PA + o) = u8;
    }
    return;
  }
  // ---- gamma_X tile (T1 remap: xcd=bid&7 owns 32 contiguous work tiles)
  bf16(*lds)[128][64] = (bf16(*)[128][64])smem;
  int wrk = (bid & 7) * 32 + (bid >> 3);
  int bm = (wrk >> 4) * 128;
  int bn = (wrk & 15) * 128;
  const int w = tid >> 6, ln = tid & 63;
  const int r8 = ln >> 3, c8 = (ln & 7) * 8;
  f32x4 acc[4][4];
#pragma unroll
  for (int i = 0; i < 4; i++)
#pragma unroll
    for (int j = 0; j < 4; j++) acc[i][j] = {0.f, 0.f, 0.f, 0.f};
  const int m0 = (w & 1) * 64, n0 = (w >> 1) * 64;
  const int fr = ln & 15, kq = (ln >> 4) * 8;
  const int esw = (fr & 7) << 3;  // T2 read-side element XOR
  for (int kt = 0; kt < 2048; kt += 64) {
#pragma unroll
    for (int q = 0; q < 4; ++q) {
      int row = (w * 4 + q) * 8 + r8;
      int sc = c8 ^ ((row & 7) << 3);  // T2 pre-swizzled global source col
      async16(K12T + (size_t)(bm + row) * 2048 + (kt + sc), &lds[0][row][c8]);
      async16(Kbf + (size_t)(bn + row) * 2048 + (kt + sc), &lds[1][row][c8]);
    }
    __syncthreads();
#pragma unroll
    for (int ks = 0; ks < 64; ks += 32) {
      bf16x8 a[4], b[4];
#pragma unroll
      for (int i = 0; i < 4; i++) {
        a[i] = *(const bf16x8*)&lds[0][m0 + i * 16 + fr][(ks + kq) ^ esw];
        b[i] = *(const bf16x8*)&lds[1][n0 + i * 16 + fr][(ks + kq) ^ esw];
      }
      __builtin_amdgcn_s_setprio(1);
#pragma unroll
      for (int i = 0; i < 4; i++)
#pragma unroll
        for (int j = 0; j < 4; j++)
          acc[i][j] = __builtin_amdgcn_mfma_f32_16x16x32_bf16(
              a[i], b[j], acc[i][j], 0, 0, 0);
      __builtin_amdgcn_s_setprio(0);
    }
    __syncthreads();
  }
  float inv = 1.f / (2000.f * __expf(ll[0]));
  float* ft = (float*)smem;  // [128][68]
  const int cr = (ln >> 4) * 4, cc = ln & 15;
  const int gtid = (tid & 7) * 8;
#pragma unroll
  for (int h = 0; h < 2; ++h) {
    if ((w >> 1) == h) {
#pragma unroll
      for (int i = 0; i < 4; i++)
#pragma unroll
        for (int j = 0; j < 4; j++)
#pragma unroll
          for (int r = 0; r < 4; r++)
            ft[(m0 + i * 16 + cr + r) * 68 + j * 16 + cc] = acc[i][j][r];
    }
    __syncthreads();
    int jbase = bn + h * 64 + gtid;
#pragma unroll
    for (int it = 0; it < 4; ++it) {
      int idx = it * 256 + tid;
      int m = idx >> 3;
      int zg = bm + m;
      size_t gb = (size_t)zg * 2048 + jbase;
      bf16x8 kh = *(const bf16x8*)(K12T + gb);
      bf16x8 klo = *(const bf16x8*)(K12TL + gb);
      bf16x8 vh, vl;
#pragma unroll
      for (int e = 0; e < 8; ++e) {
        float t1 = ft[m * 68 + gtid + e];
        float gx = ((float)kh[e] + (float)klo[e] - t1 * inv) * inv;
        bf16 hh = (bf16)gx;
        vh[e] = hh;
        vl[e] = (bf16)(gx - (float)hh);
      }
      *(bf16x8*)(gxHi + gb) = vh;
      *(bf16x8*)(gxLo + gb) = vl;
    }
    __syncthreads();
  }
}

// ---------------- k_prepX: X planes for chunk 0 -----------------------------
__global__ __launch_bounds__(256) void k_prepX(
    const bf16* __restrict__ gxHi, const bf16* __restrict__ gxLo,
    const float* __restrict__ Xm, unsigned char* __restrict__ B8, int ZC) {
  int pid = blockIdx.x;
  build_x(gxHi, gxLo, Xm, B8, (pid & 31) * 64, (pid >> 5) * 64, 0, ZC,
          threadIdx.x);
}

// --------------------- unified num(fp8)+den(bf16) GEMM ----------------------
// Split into 2 phase dispatches (R14): phase 0 = MN (num planes 0..7 + den
// side MN), phase 1 = X (planes 8..15 + den side X). 1-D grid, 96*(ZC/128)
// blocks per phase. T1 map: xcd = bid&7; num: zb = phase*8+xcd (one plane
// per XCD; 8 bm-blocks per B-tile adjacent); den: p = phase*2+(xcd>>2),
// contiguous ny range per XCD.
// T2: LDS tiles XOR-swizzled at 16-B-chunk granularity (chunk ^= row&7),
//     applied on the global_load_lds SOURCE address + the LDS read col.
__global__ __launch_bounds__(256, 2) void k_mm(
    const bf16* __restrict__ AphH, const bf16* __restrict__ AphL,
    const unsigned char* __restrict__ Aph8,
    const unsigned char* __restrict__ B8, const bf16* __restrict__ BtNh,
    const bf16* __restrict__ BtNl, const bf16* __restrict__ gxHi,
    const bf16* __restrict__ gxLo, unsigned int* __restrict__ Cpk,
    float* __restrict__ den, int ZC, int zg0, int phase) {
  const size_t PA = (size_t)1024 * 2048;
  const size_t PL8 = (size_t)ZC * 2048;  // bytes per fp8 plane
  const size_t PC = (size_t)1024 * ZC;
  __shared__ __align__(16) bf16 smem[3 * 128 * 64];  // 48 KB
  const int tid = threadIdx.x;
  const int w = tid >> 6, ln = tid & 63;
  const int fr = ln & 15;
  const int cr = (ln >> 4) * 4, cc = ln & 15;

  const int BYT = ZC >> 7;        // bn tiles per num plane
  const int xcd = blockIdx.x & 7;
  const int slot = blockIdx.x >> 3;
  const int numSlots = 8 * BYT;   // num works per XCD per phase

  if (slot < numSlots) {
    // ---------------- num plane, fp8 K=128 ----------------
    int zb = phase * 8 + xcd;
    int bn = (slot >> 3) * 128;
    int bm = (slot & 7) * 128;

    unsigned char* l8 = (unsigned char*)smem;  // 3 planes x [128][128] bytes
    const unsigned char* A0 = Aph8 + (size_t)(phase ? 2 : 0) * PA;
    const unsigned char* A1 = A0 + PA;
    const unsigned char* B = B8 + (size_t)zb * PL8;
    const int sb = phase ? 0x72727272 : 0x79797979;  // 2^-13 / 2^-6
    unsigned int* P = Cpk + (size_t)zb * PC;
    const int colb = (ln & 7) * 16;  // byte col for staging
    const int kg = (ln >> 4) * 32;   // k-byte group for frags
    const int fsw = (fr & 7) << 4;   // T2 read-side byte XOR

    f32x4 acc0[4][4], acc1[4][4];
#pragma unroll
    for (int i = 0; i < 4; i++)
#pragma unroll
      for (int j = 0; j < 4; j++) {
        acc0[i][j] = {0.f, 0.f, 0.f, 0.f};
        acc1[i][j] = {0.f, 0.f, 0.f, 0.f};
      }
    const int m0 = (w & 1) * 64, n0 = (w >> 1) * 64;

    for (int kt = 0; kt < 2048; kt += 128) {
#pragma unroll
      for (int q = 0; q < 4; ++q) {
        int row = w * 32 + q * 8 + (ln >> 3);
        int sc = colb ^ ((row & 7) << 4);  // T2 pre-swizzled source col
        async16(A0 + (size_t)(bm + row) * 2048 + kt + sc,
                l8 + row * 128 + colb);
        async16(A1 + (size_t)(bm + row) * 2048 + kt + sc,
                l8 + 16384 + row * 128 + colb);
        async16(B + (size_t)(bn + row) * 2048 + kt + sc,
                l8 + 32768 + row * 128 + colb);
      }
      __syncthreads();
      i32x8 a0[4], a1[4];
#pragma unroll
      for (int i = 0; i < 4; i++) {
        const unsigned char* pr = l8 + (m0 + i * 16 + fr) * 128;
        a0[i] = ld_swz32(pr, kg, fsw);
        a1[i] = ld_swz32(pr + 16384, kg, fsw);
      }
      __builtin_amdgcn_s_setprio(1);
#pragma unroll
      for (int j = 0; j < 4; ++j) {
        i32x8 bfv =
            ld_swz32(l8 + 32768 + (n0 + j * 16 + fr) * 128, kg, fsw);
#pragma unroll
        for (int i = 0; i < 4; ++i) {
          acc0[i][j] = __builtin_amdgcn_mfma_scale_f32_16x16x128_f8f6f4(
              a0[i], bfv, acc0[i][j], 0, 0, 0, 0x7F7F7F7F, 0, sb);
          acc1[i][j] = __builtin_amdgcn_mfma_scale_f32_16x16x128_f8f6f4(
              a1[i], bfv, acc1[i][j], 0, 0, 0, 0x7F7F7F7F, 0, sb);
        }
      }
      __builtin_amdgcn_s_setprio(0);
      __syncthreads();
    }
#pragma unroll
    for (int i = 0; i < 4; i++)
#pragma unroll
      for (int j = 0; j < 4; j++)
#pragma unroll
        for (int r = 0; r < 4; r++) {
          union { bf16 h[2]; unsigned int u; } pk;
          pk.h[0] = (bf16)acc0[i][j][r];
          pk.h[1] = (bf16)acc1[i][j][r];
          P[(size_t)(bm + m0 + i * 16 + cr + r) * ZC +
            (bn + n0 + j * 16 + cc)] = pk.u;
        }
  } else {
    // ---------------- den tile (split-bf16, 128x64) ----------------
    bf16(*lds)[64] = (bf16(*)[64])smem;
    const int kq = (ln >> 4) * 8;
    const int esw = (fr & 7) << 3;  // T2 read-side element XOR
    int j = slot - numSlots;        // [0, 4*BYT)
    int p = phase * 2 + (xcd >> 2);
    int t = (xcd & 3) * (4 * BYT) + j;  // [0, 16*BYT)
    int bm = (t & 7) * 128;
    int ny = t >> 3;                    // [0, nyT)
    int side = p >> 1, trig = p & 1;
    const bf16* Ah = AphH + (size_t)(side * 2 + trig) * PA;
    const bf16* Al = AphL + (size_t)(side * 2 + trig) * PA;
    const bf16* Bh = (side ? gxHi : BtNh) + (size_t)zg0 * 2048;
    const bf16* Bl = (side ? gxLo : BtNl) + (size_t)zg0 * 2048;
    float* C = den + (size_t)p * PC;
    int bn = ny * 64;
    const int r32 = tid >> 3, c8 = (tid & 7) * 8;

    f32x4 acc[4][2];
#pragma unroll
    for (int i = 0; i < 4; i++)
#pragma unroll
      for (int jj = 0; jj < 2; jj++) acc[i][jj] = {0.f, 0.f, 0.f, 0.f};
    const int m0 = (w & 1) * 64, n0 = (w >> 1) * 32;

    for (int kt = 0; kt < 2048; kt += 64) {
#pragma unroll
      for (int q = 0; q < 4; ++q) {
        int row = q * 32 + r32;
        int sc = c8 ^ ((row & 7) << 3);
        async16(Ah + (size_t)(bm + row) * 2048 + (kt + sc), &lds[row][c8]);
        async16(Al + (size_t)(bm + row) * 2048 + (kt + sc),
                &lds[128 + row][c8]);
      }
#pragma unroll
      for (int q = 0; q < 2; ++q) {
        int row = q * 32 + r32;
        int sc = c8 ^ ((row & 7) << 3);
        async16(Bh + (size_t)(bn + row) * 2048 + (kt + sc),
                &lds[256 + row][c8]);
        async16(Bl + (size_t)(bn + row) * 2048 + (kt + sc),
                &lds[320 + row][c8]);
      }
      __syncthreads();
#pragma unroll
      for (int ks = 0; ks < 64; ks += 32) {
        bf16x8 ah[4], alo[4], bh[2], blo[2];
#pragma unroll
        for (int i = 0; i < 4; i++) {
          ah[i]  = *(const bf16x8*)&lds[m0 + i * 16 + fr][(ks + kq) ^ esw];
          alo[i] =
              *(const bf16x8*)&lds[128 + m0 + i * 16 + fr][(ks + kq) ^ esw];
        }
#pragma unroll
        for (int jj = 0; jj < 2; jj++) {
          bh[jj] =
              *(const bf16x8*)&lds[256 + n0 + jj * 16 + fr][(ks + kq) ^ esw];
          blo[jj] =
              *(const bf16x8*)&lds[320 + n0 + jj * 16 + fr][(ks + kq) ^ esw];
        }
        __builtin_amdgcn_s_setprio(1);
#pragma unroll
        for (int i = 0; i < 4; i++)
#pragma unroll
          for (int jj = 0; jj < 2; jj++) {
            acc[i][jj] = __builtin_amdgcn_mfma_f32_16x16x32_bf16(
                alo[i], bh[jj], acc[i][jj], 0, 0, 0);
            acc[i][jj] = __builtin_amdgcn_mfma_f32_16x16x32_bf16(
                ah[i], blo[jj], acc[i][jj], 0, 0, 0);
            acc[i][jj] = __builtin_amdgcn_mfma_f32_16x16x32_bf16(
                ah[i], bh[jj], acc[i][jj], 0, 0, 0);
          }
        __builtin_amdgcn_s_setprio(0);
      }
      __syncthreads();
    }
#pragma unroll
    for (int i = 0; i < 4; i++)
#pragma unroll
      for (int jj = 0; jj < 2; jj++)
#pragma unroll
        for (int r = 0; r < 4; r++) {
          size_t idx = (size_t)(bm + m0 + i * 16 + cr + r) * ZC +
                       (bn + n0 + jj * 16 + cc);
          C[idx] = acc[i][jj][r];
        }
  }
}

// ------------- k_redprep: reduce chunk c (+ prep chunk c+1) -----------------
__device__ __forceinline__ void load8p(const unsigned int* p, float* re,
                                       float* im) {
  uint4 u0 = ((const uint4*)p)[0], u1 = ((const uint4*)p)[1];
  re[0] = __uint_as_float(u0.x << 16); im[0] = __uint_as_float(u0.x & 0xffff0000u);
  re[1] = __uint_as_float(u0.y << 16); im[1] = __uint_as_float(u0.y & 0xffff0000u);
  re[2] = __uint_as_float(u0.z << 16); im[2] = __uint_as_float(u0.z & 0xffff0000u);
  re[3] = __uint_as_float(u0.w << 16); im[3] = __uint_as_float(u0.w & 0xffff0000u);
  re[4] = __uint_as_float(u1.x << 16); im[4] = __uint_as_float(u1.x & 0xffff0000u);
  re[5] = __uint_as_float(u1.y << 16); im[5] = __uint_as_float(u1.y & 0xffff0000u);
  re[6] = __uint_as_float(u1.z << 16); im[6] = __uint_as_float(u1.z & 0xffff0000u);
  re[7] = __uint_as_float(u1.w << 16); im[7] = __uint_as_float(u1.w & 0xffff0000u);
}
__device__ __forceinline__ void load8d(const float* p, float* o) {
  float4 f0 = ((const float4*)p)[0], f1 = ((const float4*)p)[1];
  o[0] = f0.x; o[1] = f0.y; o[2] = f0.z; o[3] = f0.w;
  o[4] = f1.x; o[5] = f1.y; o[6] = f1.z; o[7] = f1.w;
}

// 1000 reduce blocks: one a-row per block, 8 z per thread (8-wide loads —
// ILP via 40 independent 16B loads/thread), 1000 same-address atomics.
// (R13 lesson: 2000 blocks/16B loads lost ~23us — atomic serialization +
// halved per-thread ILP.)
__global__ __launch_bounds__(256) void k_redprep(
    const unsigned int* __restrict__ Cpk, const float* __restrict__ den,
    float* __restrict__ out, const float* __restrict__ gMN,
    const float* __restrict__ Mm, const bf16* __restrict__ gxHi,
    const bf16* __restrict__ gxLo, const float* __restrict__ Xm,
    unsigned char* __restrict__ B8Next, int ZC, int zg0) {
  __shared__ float sm[64][65];
  const int bid = blockIdx.x, tid = threadIdx.x;
  if (bid >= 1000) {
    int pid = bid - 1000;
    int j0 = (pid & 31) * 64, zl0 = (pid >> 5) * 64;
    int zg0n = zg0 + ZC;
    build_mn(gMN, Mm, B8Next, j0, zl0, zg0n, ZC, tid, sm);
    build_x(gxHi, gxLo, Xm, B8Next, j0, zl0, zg0n, ZC, tid);
    return;
  }
  const size_t PS = (size_t)1024 * ZC;
  const int a = bid;
  float acc = 0.f;
  for (int z = tid * 8; z < ZC; z += 2048) {
    if (zg0 + z >= 2000) break;
    size_t base = (size_t)a * ZC + z;
    float mdr[8], mdi[8], xdr[8], xdi[8], im[8], ix[8];
    load8d(den + 0 * PS + base, mdr);
    load8d(den + 1 * PS + base, mdi);
    load8d(den + 2 * PS + base, xdr);
    load8d(den + 3 * PS + base, xdi);
#pragma unroll
    for (int e = 0; e < 8; ++e) {
      im[e] = 1.f / (mdr[e] * mdr[e] + mdi[e] * mdi[e]);
      ix[e] = 1.f / (xdr[e] * xdr[e] + xdi[e] * xdi[e]);
    }
#pragma unroll
    for (int d = 0; d < 8; ++d) {
      float ar[8], ai[8], br[8], bi[8];
      load8p(Cpk + (size_t)d * PS + base, ar, ai);
      load8p(Cpk + (size_t)(8 + d) * PS + base, br, bi);
#pragma unroll
      for (int e = 0; e < 8; ++e) {
        float r1 = (ar[e] * mdr[e] + ai[e] * mdi[e]) * im[e];
        float i1 = (ai[e] * mdr[e] - ar[e] * mdi[e]) * im[e];
        float r2 = (br[e] * xdr[e] + bi[e] * xdi[e]) * ix[e];
        float i2 = (bi[e] * xdr[e] - br[e] * xdi[e]) * ix[e];
        float dr = r1 - r2, di = i1 - i2;
        acc += dr * dr + di * di;
      }
    }
  }
  for (int off = 32; off; off >>= 1) acc += __shfl_down(acc, off, 64);
  __shared__ float red[4];
  if (!(tid & 63)) red[tid >> 6] = acc;
  __syncthreads();
  if (!tid)
    atomicAdd(out, (red[0] + red[1] + red[2] + red[3]) * (1.f / 2000000.f));
}

// ============================================================================
extern "C" void kernel_launch(void* const* d_in, const int* in_sizes, int n_in,
                              void* d_out, int out_size, void* d_ws,
                              size_t ws_size, hipStream_t stream) {
  const float* Mm  = (const float*)d_in[0];
  const float* Nm  = (const float*)d_in[1];
  const float* Xm  = (const float*)d_in[2];
  const float* ll  = (const float*)d_in[3];
  const float* K11 = (const float*)d_in[4];
  const float* K12 = (const float*)d_in[5];
  const float* gMN = (const float*)d_in[6];
  const float* gN  = (const float*)d_in[7];
  const float* al  = (const float*)d_in[8];

  char* ws = (char*)d_ws;
  const size_t MB = 1024 * 1024;
  bf16* AphH = (bf16*)(ws);                       // 16 MB
  bf16* AphL = (bf16*)(ws + 16 * MB);             // 16 MB
  unsigned char* Aph8 = (unsigned char*)(ws + 32 * MB);  // 8 MB (fp8 phases)
  bf16* gxHi = (bf16*)(ws + 40 * MB);             // 8 MB
  bf16* gxLo = (bf16*)(ws + 48 * MB);             // 8 MB
  bf16* BtNh = (bf16*)(ws + 56 * MB);             // 8 MB
  bf16* BtNl = (bf16*)(ws + 64 * MB);             // 8 MB
  char* chunkRgn = ws + 72 * MB;

  // chunk: B8 16 fp8 planes (32768*ZC) | den (16384*ZC) | Cpk (65536*ZC)
  // transients (Kbf/K12T/K12TL, 24 MB) after the chunk region.
  size_t fixedNeed = 96 * MB;  // 72 fixed + 24 transients
  size_t avail = (ws_size > fixedNeed) ? ws_size - fixedNeed : 0;
  int ZC = 2048;
  while (ZC > 128 && (size_t)114688 * ZC > avail) ZC >>= 1;
  int NC = 2048 / ZC;
  unsigned char* B8c = (unsigned char*)(chunkRgn);
  float* denc = (float*)(chunkRgn + (size_t)32768 * ZC);
  unsigned int* Cpkc = (unsigned int*)(chunkRgn + (size_t)49152 * ZC);
  char* trans = chunkRgn + (size_t)114688 * ZC;
  bf16* Kbf   = (bf16*)(trans);
  bf16* K12T  = (bf16*)(trans + 8 * MB);
  bf16* K12TL = (bf16*)(trans + 16 * MB);

  int NBP = 32 * (ZC / 64);   // prep blocks per chunk
  int GMM = 96 * (ZC >> 7);   // k_mm blocks PER PHASE (num 64BYT + den 32BYT)

  k_cvt<<<dim3(4096), dim3(256), 0, stream>>>(K11, K12, gN, Kbf, K12T, K12TL,
                                              BtNh, BtNl, (float*)d_out);
  k_big<<<dim3(1280 + NBP), dim3(256), 0, stream>>>(
      K12T, K12TL, Kbf, ll, al, Nm, Xm, gMN, Mm, gxHi, gxLo, AphH, AphL, Aph8,
      B8c, ZC);
  k_prepX<<<dim3(NBP), dim3(256), 0, stream>>>(gxHi, gxLo, Xm, B8c, ZC);
  for (int c = 0; c < NC; ++c) {
    int zg0 = c * ZC;
    k_mm<<<dim3(GMM), dim3(256), 0, stream>>>(
        AphH, AphL, Aph8, B8c, BtNh, BtNl, gxHi, gxLo, Cpkc, denc, ZC, zg0, 0);
    k_mm<<<dim3(GMM), dim3(256), 0, stream>>>(
        AphH, AphL, Aph8, B8c, BtNh, BtNl, gxHi, gxLo, Cpkc, denc, ZC, zg0, 1);
    int nblk = (c + 1 < NC) ? 1000 + NBP : 1000;
    k_redprep<<<dim3(nblk), dim3(256), 0, stream>>>(
        Cpkc, denc, (float*)d_out, gMN, Mm, gxHi, gxLo, Xm, B8c, ZC, zg0);
  }
  (void)in_sizes; (void)n_in; (void)out_size;
}

// Round 5
// 467.324 us; speedup vs baseline: 1.2121x; 1.2121x over previous
//
#include <hip/hip_runtime.h>

// ============================================================================
// XModel_66795331387584: complex phase-feature ridge loss on MI355X (gfx950)
//
// loss = mean_{a,z} sum_d | num_MN/den_MN - num_X/den_X |^2
// den path: split-bf16 (hi+lo), fp32 out (tail-dominated 1/|den|^2).
// gamma_X via 1-term Neumann: gx = (K12 - K@K12/reg)/reg (rel err 4e-6).
//
// R10: num GEMM on MX-fp8 (mfma_scale 16x16x128, uniform E8M0 scales).
// R11: T1 XCD-chunked work map + T2 LDS XOR swizzle + T5 setprio in k_mm /
//      k_big GEMM. k_mm: 153->118us (93% of mixed MFMA pipe roofline).
// R12 LESSON: __launch_bounds__(256,3) VGPR cap 84 < 128-reg acc -> spill.
// R13 LESSON: 2000-block redprep regrid lost ~23us (same-address atomic
//      serialization + halved per-thread ILP).
// R14 LESSON: splitting k_mm into 2 phase dispatches cost +40us (two tails,
//      no cross-phase co-scheduling, FETCH 98->131MB). But it bounded the
//      hidden kernels: k_cvt/k_big/k_prepX/k_redprep are each <80us.
// R15: revert k_mm to the R13 combined form (best measured, 121us); keep
//      k_redprep at 1000 blocks/8-wide (max TLP at full ILP); vectorize
//      k_cvt/build_mn staging loads to float4 (G13; 2000%4==0 so the
//      col guard is exact at float4 granularity).
// ============================================================================

typedef __bf16 bf16;
typedef __bf16 bf16x8 __attribute__((ext_vector_type(8)));
typedef float f32x4 __attribute__((ext_vector_type(4)));
typedef int i32x8 __attribute__((ext_vector_type(8)));
typedef int i32x4 __attribute__((ext_vector_type(4)));

#define AS1 __attribute__((address_space(1)))
#define AS3 __attribute__((address_space(3)))

__device__ __forceinline__ void async16(const void* g, void* l) {
  __builtin_amdgcn_global_load_lds((AS1 const unsigned int*)g,
                                   (AS3 unsigned int*)l, 16, 0, 0);
}

__device__ __forceinline__ unsigned int pk4f8(float a, float b, float c,
                                              float d) {
  int w = __builtin_amdgcn_cvt_pk_fp8_f32(a, b, 0, false);
  w = __builtin_amdgcn_cvt_pk_fp8_f32(c, d, w, true);
  return (unsigned int)w;
}

// 32-B fragment read from a 128-B-row LDS tile with 16-B-chunk XOR swizzle.
__device__ __forceinline__ i32x8 ld_swz32(const unsigned char* rowp, int kg,
                                          int fsw) {
  i32x4 lo = *(const i32x4*)(rowp + (kg ^ fsw));
  i32x4 hi = *(const i32x4*)(rowp + ((kg + 16) ^ fsw));
  i32x8 v;
  v[0] = lo[0]; v[1] = lo[1]; v[2] = lo[2]; v[3] = lo[3];
  v[4] = hi[0]; v[5] = hi[1]; v[6] = hi[2]; v[7] = hi[3];
  return v;
}

// Stage a 64x64 f32 tile (row-major src, stride 2000) into LDS t[64][65]
// with float4 loads. 2000%4==0 -> col guard exact at float4 granularity.
__device__ __forceinline__ void stage64x64(const float* __restrict__ src,
                                           int row0, int col0,
                                           float (*t)[65], int tid) {
#pragma unroll
  for (int it = 0; it < 4; ++it) {
    int e = it * 256 + tid;           // 0..1023
    int r = e >> 4, c4 = (e & 15) * 4;
    float4 v = {0.f, 0.f, 0.f, 0.f};
    if (row0 + r < 2000 && col0 + c4 < 2000)
      v = *(const float4*)(src + (size_t)(row0 + r) * 2000 + col0 + c4);
    t[r][c4] = v.x; t[r][c4 + 1] = v.y; t[r][c4 + 2] = v.z; t[r][c4 + 3] = v.w;
  }
}

// -------- B-plane builders (fp8, 64x64 tile) --------------------------------
// planes 0..7: 64 * M_d * gMN^T ; planes 8..15: 8192 * X_d * gx
__device__ __forceinline__ void build_mn(const float* __restrict__ gMN,
                                         const float* __restrict__ Mm,
                                         unsigned char* __restrict__ B8,
                                         int j0, int zl0, int zg0, int ZC,
                                         int tid, float (*t)[65]) {
  const size_t PL = (size_t)ZC * 2048;
  int zg = zg0 + zl0;
  stage64x64(gMN, j0, zg, t, tid);
  __syncthreads();
  const float4* M4 = (const float4*)Mm;
#pragma unroll
  for (int it = 0; it < 2; ++it) {
    int idx = it * 256 + tid;
    int zr = idx >> 3, c8 = (idx & 7) * 8;
    float g[8], mrow[8][8];
#pragma unroll
    for (int e = 0; e < 8; ++e) {
      g[e] = 64.f * t[c8 + e][zr];
      int jj = j0 + c8 + e;
      if (jj < 2000) {
        float4 ma = M4[jj * 2], mb = M4[jj * 2 + 1];
        mrow[e][0] = ma.x; mrow[e][1] = ma.y; mrow[e][2] = ma.z;
        mrow[e][3] = ma.w; mrow[e][4] = mb.x; mrow[e][5] = mb.y;
        mrow[e][6] = mb.z; mrow[e][7] = mb.w;
      } else {
#pragma unroll
        for (int d = 0; d < 8; ++d) mrow[e][d] = 0.f;
      }
    }
    size_t ob = (size_t)(zl0 + zr) * 2048 + j0 + c8;
#pragma unroll
    for (int d = 0; d < 8; ++d) {
      uint2 u;
      u.x = pk4f8(g[0] * mrow[0][d], g[1] * mrow[1][d], g[2] * mrow[2][d],
                  g[3] * mrow[3][d]);
      u.y = pk4f8(g[4] * mrow[4][d], g[5] * mrow[5][d], g[6] * mrow[6][d],
                  g[7] * mrow[7][d]);
      *(uint2*)(B8 + (size_t)d * PL + ob) = u;
    }
  }
}

__device__ __forceinline__ void build_x(const bf16* __restrict__ gxHi,
                                        const bf16* __restrict__ gxLo,
                                        const float* __restrict__ Xm,
                                        unsigned char* __restrict__ B8,
                                        int j0, int zl0, int zg0, int ZC,
                                        int tid) {
  const size_t PL = (size_t)ZC * 2048;
  const float4* X4 = (const float4*)Xm;
#pragma unroll
  for (int it = 0; it < 2; ++it) {
    int idx = it * 256 + tid;
    int zr = idx >> 3, c8 = (idx & 7) * 8;
    size_t gb = (size_t)(zg0 + zl0 + zr) * 2048 + j0 + c8;
    bf16x8 vh = *(const bf16x8*)(gxHi + gb);
    bf16x8 vl = *(const bf16x8*)(gxLo + gb);
    float gx[8], xr[8][8];
#pragma unroll
    for (int e = 0; e < 8; ++e) {
      gx[e] = 8192.f * ((float)vh[e] + (float)vl[e]);
      int jj = j0 + c8 + e;
      if (jj < 2000) {
        float4 xa = X4[jj * 2], xb = X4[jj * 2 + 1];
        xr[e][0] = xa.x; xr[e][1] = xa.y; xr[e][2] = xa.z; xr[e][3] = xa.w;
        xr[e][4] = xb.x; xr[e][5] = xb.y; xr[e][6] = xb.z; xr[e][7] = xb.w;
      } else {
#pragma unroll
        for (int d = 0; d < 8; ++d) xr[e][d] = 0.f;
      }
    }
    size_t ob = (size_t)(zl0 + zr) * 2048 + j0 + c8;
#pragma unroll
    for (int d = 0; d < 8; ++d) {
      uint2 u;
      u.x = pk4f8(gx[0] * xr[0][d], gx[1] * xr[1][d], gx[2] * xr[2][d],
                  gx[3] * xr[3][d]);
      u.y = pk4f8(gx[4] * xr[4][d], gx[5] * xr[5][d], gx[6] * xr[6][d],
                  gx[7] * xr[7][d]);
      *(uint2*)(B8 + (size_t)(8 + d) * PL + ob) = u;
    }
  }
}

// ---------------- k_cvt: converts + gN planes + out zero --------------------
__global__ __launch_bounds__(256) void k_cvt(
    const float* __restrict__ K11, const float* __restrict__ K12,
    const float* __restrict__ gN, bf16* __restrict__ Kbf,
    bf16* __restrict__ K12T, bf16* __restrict__ K12TL,
    bf16* __restrict__ BtNh, bf16* __restrict__ BtNl,
    float* __restrict__ out) {
  __shared__ float t[64][65];
  const int bid = blockIdx.x, tid = threadIdx.x;
  if (bid < 2048) {
    if (bid == 0 && tid == 0) out[0] = 0.f;
    int e = (bid * 256 + tid) * 8;
    int j = e >> 11, k = e & 2047;
    bf16x8 v;
    if (j < 2000 && k < 2000) {
      const float4* s = (const float4*)(K11 + (size_t)j * 2000 + k);
      float4 f0 = s[0], f1 = s[1];
      v[0] = (bf16)f0.x; v[1] = (bf16)f0.y; v[2] = (bf16)f0.z; v[3] = (bf16)f0.w;
      v[4] = (bf16)f1.x; v[5] = (bf16)f1.y; v[6] = (bf16)f1.z; v[7] = (bf16)f1.w;
    } else {
      for (int i = 0; i < 8; ++i) v[i] = (bf16)0.f;
    }
    *(bf16x8*)(Kbf + e) = v;
  } else {
    bool isK12 = bid < 3072;
    const float* src = isK12 ? K12 : gN;
    bf16* dh = isK12 ? K12T : BtNh;
    bf16* dl = isK12 ? K12TL : BtNl;
    int b2 = bid - (isK12 ? 2048 : 3072);
    int j0 = (b2 & 31) * 64, z0 = (b2 >> 5) * 64;
    stage64x64(src, j0, z0, t, tid);
    __syncthreads();
#pragma unroll
    for (int it = 0; it < 2; ++it) {
      int idx = it * 256 + tid;
      int zr = idx >> 3, c8 = (idx & 7) * 8;
      bf16x8 vh, vl;
#pragma unroll
      for (int e = 0; e < 8; ++e) {
        float g = t[c8 + e][zr];
        bf16 h = (bf16)g;
        vh[e] = h;
        vl[e] = (bf16)(g - (float)h);
      }
      size_t ob = (size_t)(z0 + zr) * 2048 + j0 + c8;
      *(bf16x8*)(dh + ob) = vh;
      *(bf16x8*)(dl + ob) = vl;
    }
  }
}

// --------- k_big: gemm1 tiles + phases (+fp8) + prepMN(chunk0) --------------
__global__ __launch_bounds__(256, 2) void k_big(
    const bf16* __restrict__ K12T, const bf16* __restrict__ K12TL,
    const bf16* __restrict__ Kbf, const float* __restrict__ ll,
    const float* __restrict__ al, const float* __restrict__ Nm,
    const float* __restrict__ Xm, const float* __restrict__ gMN,
    const float* __restrict__ Mm, bf16* __restrict__ gxHi,
    bf16* __restrict__ gxLo, bf16* __restrict__ AphH,
    bf16* __restrict__ AphL, unsigned char* __restrict__ Aph8,
    unsigned char* __restrict__ B8, int ZC) {
  __shared__ __align__(16) char smem[34816];
  const int tid = threadIdx.x;
  const int bid = blockIdx.x;
  if (bid >= 1280) {
    int pid = bid - 1280;
    build_mn(gMN, Mm, B8, (pid & 31) * 64, (pid >> 5) * 64, 0, ZC, tid,
             (float(*)[65])smem);
    return;
  }
  if (bid >= 256) {
    // ---- phases: a = bid-256, 8 j per thread
    const size_t PA = (size_t)1024 * 2048;
    int a = bid - 256;
    int j0 = tid * 8;
    float vc[4][8];
    if (a < 1000) {
      const float4* A4 = (const float4*)al;
      const float4* N4 = (const float4*)Nm;
      const float4* X4 = (const float4*)Xm;
      float4 a0 = A4[a * 2], a1 = A4[a * 2 + 1];
#pragma unroll
      for (int e = 0; e < 8; ++e) {
        int j = j0 + e;
        if (j < 2000) {
          float4 n0 = N4[j * 2], n1 = N4[j * 2 + 1];
          float4 x0 = X4[j * 2], x1 = X4[j * 2 + 1];
          float pn = a0.x * n0.x + a0.y * n0.y + a0.z * n0.z + a0.w * n0.w +
                     a1.x * n1.x + a1.y * n1.y + a1.z * n1.z + a1.w * n1.w;
          float px = a0.x * x0.x + a0.y * x0.y + a0.z * x0.z + a0.w * x0.w +
                     a1.x * x1.x + a1.y * x1.y + a1.z * x1.z + a1.w * x1.w;
          __sincosf(pn, &vc[1][e], &vc[0][e]);
          __sincosf(px, &vc[3][e], &vc[2][e]);
        } else {
          vc[0][e] = vc[1][e] = vc[2][e] = vc[3][e] = 0.f;
        }
      }
    } else {
#pragma unroll
      for (int p = 0; p < 4; ++p)
#pragma unroll
        for (int e = 0; e < 8; ++e) vc[p][e] = 0.f;
    }
    size_t o = (size_t)a * 2048 + j0;
#pragma unroll
    for (int p = 0; p < 4; ++p) {
      bf16x8 vh, vl;
#pragma unroll
      for (int e = 0; e < 8; ++e) {
        bf16 h = (bf16)vc[p][e];
        vh[e] = h;
        vl[e] = (bf16)(vc[p][e] - (float)h);
      }
      *(bf16x8*)(AphH + p * PA + o) = vh;
      *(bf16x8*)(AphL + p * PA + o) = vl;
      uint2 u8;
      u8.x = pk4f8(vc[p][0], vc[p][1], vc[p][2], vc[p][3]);
      u8.y = pk4f8(vc[p][4], vc[p][5], vc[p][6], vc[p][7]);
      *(uint2*)(Aph8 + p * PA + o) = u8;
    }
    return;
  }
  // ---- gamma_X tile (T1 remap: xcd=bid&7 owns 32 contiguous work tiles)
  bf16(*lds)[128][64] = (bf16(*)[128][64])smem;
  int wrk = (bid & 7) * 32 + (bid >> 3);
  int bm = (wrk >> 4) * 128;
  int bn = (wrk & 15) * 128;
  const int w = tid >> 6, ln = tid & 63;
  const int r8 = ln >> 3, c8 = (ln & 7) * 8;
  f32x4 acc[4][4];
#pragma unroll
  for (int i = 0; i < 4; i++)
#pragma unroll
    for (int j = 0; j < 4; j++) acc[i][j] = {0.f, 0.f, 0.f, 0.f};
  const int m0 = (w & 1) * 64, n0 = (w >> 1) * 64;
  const int fr = ln & 15, kq = (ln >> 4) * 8;
  const int esw = (fr & 7) << 3;  // T2 read-side element XOR
  for (int kt = 0; kt < 2048; kt += 64) {
#pragma unroll
    for (int q = 0; q < 4; ++q) {
      int row = (w * 4 + q) * 8 + r8;
      int sc = c8 ^ ((row & 7) << 3);  // T2 pre-swizzled global source col
      async16(K12T + (size_t)(bm + row) * 2048 + (kt + sc), &lds[0][row][c8]);
      async16(Kbf + (size_t)(bn + row) * 2048 + (kt + sc), &lds[1][row][c8]);
    }
    __syncthreads();
#pragma unroll
    for (int ks = 0; ks < 64; ks += 32) {
      bf16x8 a[4], b[4];
#pragma unroll
      for (int i = 0; i < 4; i++) {
        a[i] = *(const bf16x8*)&lds[0][m0 + i * 16 + fr][(ks + kq) ^ esw];
        b[i] = *(const bf16x8*)&lds[1][n0 + i * 16 + fr][(ks + kq) ^ esw];
      }
      __builtin_amdgcn_s_setprio(1);
#pragma unroll
      for (int i = 0; i < 4; i++)
#pragma unroll
        for (int j = 0; j < 4; j++)
          acc[i][j] = __builtin_amdgcn_mfma_f32_16x16x32_bf16(
              a[i], b[j], acc[i][j], 0, 0, 0);
      __builtin_amdgcn_s_setprio(0);
    }
    __syncthreads();
  }
  float inv = 1.f / (2000.f * __expf(ll[0]));
  float* ft = (float*)smem;  // [128][68]
  const int cr = (ln >> 4) * 4, cc = ln & 15;
  const int gtid = (tid & 7) * 8;
#pragma unroll
  for (int h = 0; h < 2; ++h) {
    if ((w >> 1) == h) {
#pragma unroll
      for (int i = 0; i < 4; i++)
#pragma unroll
        for (int j = 0; j < 4; j++)
#pragma unroll
          for (int r = 0; r < 4; r++)
            ft[(m0 + i * 16 + cr + r) * 68 + j * 16 + cc] = acc[i][j][r];
    }
    __syncthreads();
    int jbase = bn + h * 64 + gtid;
#pragma unroll
    for (int it = 0; it < 4; ++it) {
      int idx = it * 256 + tid;
      int m = idx >> 3;
      int zg = bm + m;
      size_t gb = (size_t)zg * 2048 + jbase;
      bf16x8 kh = *(const bf16x8*)(K12T + gb);
      bf16x8 klo = *(const bf16x8*)(K12TL + gb);
      bf16x8 vh, vl;
#pragma unroll
      for (int e = 0; e < 8; ++e) {
        float t1 = ft[m * 68 + gtid + e];
        float gx = ((float)kh[e] + (float)klo[e] - t1 * inv) * inv;
        bf16 hh = (bf16)gx;
        vh[e] = hh;
        vl[e] = (bf16)(gx - (float)hh);
      }
      *(bf16x8*)(gxHi + gb) = vh;
      *(bf16x8*)(gxLo + gb) = vl;
    }
    __syncthreads();
  }
}

// ---------------- k_prepX: X planes for chunk 0 -----------------------------
__global__ __launch_bounds__(256) void k_prepX(
    const bf16* __restrict__ gxHi, const bf16* __restrict__ gxLo,
    const float* __restrict__ Xm, unsigned char* __restrict__ B8, int ZC) {
  int pid = blockIdx.x;
  build_x(gxHi, gxLo, Xm, B8, (pid & 31) * 64, (pid >> 5) * 64, 0, ZC,
          threadIdx.x);
}

// --------------------- unified num(fp8)+den(bf16) GEMM ----------------------
// 1-D grid, 192*(ZC/128) blocks. T1 XCD-chunked map: xcd = bid&7 processes
//   slot<16*BYT : num works — zb = xcd*2 + slot/(8*BYT) (XCD owns one cos/sin
//                 A pair, ~4MB, near-L2-resident; 8 bm-blocks per B-tile are
//                 adjacent so each B-tile is fetched into ONE XCD's L2)
//   else        : den works — p = xcd>>1, ny half = xcd&1.
// T2: LDS tiles XOR-swizzled at 16-B-chunk granularity (chunk ^= row&7),
//     applied on the global_load_lds SOURCE address + the LDS read col.
__global__ __launch_bounds__(256, 2) void k_mm(
    const bf16* __restrict__ AphH, const bf16* __restrict__ AphL,
    const unsigned char* __restrict__ Aph8,
    const unsigned char* __restrict__ B8, const bf16* __restrict__ BtNh,
    const bf16* __restrict__ BtNl, const bf16* __restrict__ gxHi,
    const bf16* __restrict__ gxLo, unsigned int* __restrict__ Cpk,
    float* __restrict__ den, int ZC, int zg0) {
  const size_t PA = (size_t)1024 * 2048;
  const size_t PL8 = (size_t)ZC * 2048;  // bytes per fp8 plane
  const size_t PC = (size_t)1024 * ZC;
  __shared__ __align__(16) bf16 smem[3 * 128 * 64];  // 48 KB
  const int tid = threadIdx.x;
  const int w = tid >> 6, ln = tid & 63;
  const int fr = ln & 15;
  const int cr = (ln >> 4) * 4, cc = ln & 15;

  const int BYT = ZC >> 7;        // bn tiles per num plane
  const int nyT = ZC >> 6;        // den ny tiles
  const int xcd = blockIdx.x & 7;
  const int slot = blockIdx.x >> 3;
  const int numSlots = 16 * BYT;  // num works per XCD

  if (slot < numSlots) {
    // ---------------- num pair-plane, fp8 K=128 ----------------
    const int half = numSlots >> 1;  // 8*BYT (pow2)
    int zb = xcd * 2 + (slot >= half ? 1 : 0);
    int rem = slot & (half - 1);
    int bn = (rem >> 3) * 128;
    int bm = (rem & 7) * 128;

    unsigned char* l8 = (unsigned char*)smem;  // 3 planes x [128][128] bytes
    const unsigned char* A0 = Aph8 + (size_t)(zb < 8 ? 0 : 2) * PA;
    const unsigned char* A1 = A0 + PA;
    const unsigned char* B = B8 + (size_t)zb * PL8;
    const int sb = (zb < 8) ? 0x79797979 : 0x72727272;  // 2^-6 / 2^-13
    unsigned int* P = Cpk + (size_t)zb * PC;
    const int colb = (ln & 7) * 16;  // byte col for staging
    const int kg = (ln >> 4) * 32;   // k-byte group for frags
    const int fsw = (fr & 7) << 4;   // T2 read-side byte XOR

    f32x4 acc0[4][4], acc1[4][4];
#pragma unroll
    for (int i = 0; i < 4; i++)
#pragma unroll
      for (int j = 0; j < 4; j++) {
        acc0[i][j] = {0.f, 0.f, 0.f, 0.f};
        acc1[i][j] = {0.f, 0.f, 0.f, 0.f};
      }
    const int m0 = (w & 1) * 64, n0 = (w >> 1) * 64;

    for (int kt = 0; kt < 2048; kt += 128) {
#pragma unroll
      for (int q = 0; q < 4; ++q) {
        int row = w * 32 + q * 8 + (ln >> 3);
        int sc = colb ^ ((row & 7) << 4);  // T2 pre-swizzled source col
        async16(A0 + (size_t)(bm + row) * 2048 + kt + sc,
                l8 + row * 128 + colb);
        async16(A1 + (size_t)(bm + row) * 2048 + kt + sc,
                l8 + 16384 + row * 128 + colb);
        async16(B + (size_t)(bn + row) * 2048 + kt + sc,
                l8 + 32768 + row * 128 + colb);
      }
      __syncthreads();
      i32x8 a0[4], a1[4];
#pragma unroll
      for (int i = 0; i < 4; i++) {
        const unsigned char* pr = l8 + (m0 + i * 16 + fr) * 128;
        a0[i] = ld_swz32(pr, kg, fsw);
        a1[i] = ld_swz32(pr + 16384, kg, fsw);
      }
      __builtin_amdgcn_s_setprio(1);
#pragma unroll
      for (int j = 0; j < 4; ++j) {
        i32x8 bfv =
            ld_swz32(l8 + 32768 + (n0 + j * 16 + fr) * 128, kg, fsw);
#pragma unroll
        for (int i = 0; i < 4; ++i) {
          acc0[i][j] = __builtin_amdgcn_mfma_scale_f32_16x16x128_f8f6f4(
              a0[i], bfv, acc0[i][j], 0, 0, 0, 0x7F7F7F7F, 0, sb);
          acc1[i][j] = __builtin_amdgcn_mfma_scale_f32_16x16x128_f8f6f4(
              a1[i], bfv, acc1[i][j], 0, 0, 0, 0x7F7F7F7F, 0, sb);
        }
      }
      __builtin_amdgcn_s_setprio(0);
      __syncthreads();
    }
#pragma unroll
    for (int i = 0; i < 4; i++)
#pragma unroll
      for (int j = 0; j < 4; j++)
#pragma unroll
        for (int r = 0; r < 4; r++) {
          union { bf16 h[2]; unsigned int u; } pk;
          pk.h[0] = (bf16)acc0[i][j][r];
          pk.h[1] = (bf16)acc1[i][j][r];
          P[(size_t)(bm + m0 + i * 16 + cr + r) * ZC +
            (bn + n0 + j * 16 + cc)] = pk.u;
        }
  } else {
    // ---------------- den tile (split-bf16, 128x64) ----------------
    bf16(*lds)[64] = (bf16(*)[64])smem;
    const int kq = (ln >> 4) * 8;
    const int esw = (fr & 7) << 3;  // T2 read-side element XOR
    int j = slot - numSlots;        // 0 .. 4*nyT-1
    int p = xcd >> 1;
    int ny = (xcd & 1) * (nyT >> 1) + (j >> 3);
    int side = p >> 1, trig = p & 1;
    const bf16* Ah = AphH + (size_t)(side * 2 + trig) * PA;
    const bf16* Al = AphL + (size_t)(side * 2 + trig) * PA;
    const bf16* Bh = (side ? gxHi : BtNh) + (size_t)zg0 * 2048;
    const bf16* Bl = (side ? gxLo : BtNl) + (size_t)zg0 * 2048;
    float* C = den + (size_t)p * PC;
    int bm = (j & 7) * 128, bn = ny * 64;
    const int r32 = tid >> 3, c8 = (tid & 7) * 8;

    f32x4 acc[4][2];
#pragma unroll
    for (int i = 0; i < 4; i++)
#pragma unroll
      for (int jj = 0; jj < 2; jj++) acc[i][jj] = {0.f, 0.f, 0.f, 0.f};
    const int m0 = (w & 1) * 64, n0 = (w >> 1) * 32;

    for (int kt = 0; kt < 2048; kt += 64) {
#pragma unroll
      for (int q = 0; q < 4; ++q) {
        int row = q * 32 + r32;
        int sc = c8 ^ ((row & 7) << 3);
        async16(Ah + (size_t)(bm + row) * 2048 + (kt + sc), &lds[row][c8]);
        async16(Al + (size_t)(bm + row) * 2048 + (kt + sc),
                &lds[128 + row][c8]);
      }
#pragma unroll
      for (int q = 0; q < 2; ++q) {
        int row = q * 32 + r32;
        int sc = c8 ^ ((row & 7) << 3);
        async16(Bh + (size_t)(bn + row) * 2048 + (kt + sc),
                &lds[256 + row][c8]);
        async16(Bl + (size_t)(bn + row) * 2048 + (kt + sc),
                &lds[320 + row][c8]);
      }
      __syncthreads();
#pragma unroll
      for (int ks = 0; ks < 64; ks += 32) {
        bf16x8 ah[4], alo[4], bh[2], blo[2];
#pragma unroll
        for (int i = 0; i < 4; i++) {
          ah[i]  = *(const bf16x8*)&lds[m0 + i * 16 + fr][(ks + kq) ^ esw];
          alo[i] =
              *(const bf16x8*)&lds[128 + m0 + i * 16 + fr][(ks + kq) ^ esw];
        }
#pragma unroll
        for (int jj = 0; jj < 2; jj++) {
          bh[jj] =
              *(const bf16x8*)&lds[256 + n0 + jj * 16 + fr][(ks + kq) ^ esw];
          blo[jj] =
              *(const bf16x8*)&lds[320 + n0 + jj * 16 + fr][(ks + kq) ^ esw];
        }
        __builtin_amdgcn_s_setprio(1);
#pragma unroll
        for (int i = 0; i < 4; i++)
#pragma unroll
          for (int jj = 0; jj < 2; jj++) {
            acc[i][jj] = __builtin_amdgcn_mfma_f32_16x16x32_bf16(
                alo[i], bh[jj], acc[i][jj], 0, 0, 0);
            acc[i][jj] = __builtin_amdgcn_mfma_f32_16x16x32_bf16(
                ah[i], blo[jj], acc[i][jj], 0, 0, 0);
            acc[i][jj] = __builtin_amdgcn_mfma_f32_16x16x32_bf16(
                ah[i], bh[jj], acc[i][jj], 0, 0, 0);
          }
        __builtin_amdgcn_s_setprio(0);
      }
      __syncthreads();
    }
#pragma unroll
    for (int i = 0; i < 4; i++)
#pragma unroll
      for (int jj = 0; jj < 2; jj++)
#pragma unroll
        for (int r = 0; r < 4; r++) {
          size_t idx = (size_t)(bm + m0 + i * 16 + cr + r) * ZC +
                       (bn + n0 + jj * 16 + cc);
          C[idx] = acc[i][jj][r];
        }
  }
}

// ------------- k_redprep: reduce chunk c (+ prep chunk c+1) -----------------
__device__ __forceinline__ void load8p(const unsigned int* p, float* re,
                                       float* im) {
  uint4 u0 = ((const uint4*)p)[0], u1 = ((const uint4*)p)[1];
  re[0] = __uint_as_float(u0.x << 16); im[0] = __uint_as_float(u0.x & 0xffff0000u);
  re[1] = __uint_as_float(u0.y << 16); im[1] = __uint_as_float(u0.y & 0xffff0000u);
  re[2] = __uint_as_float(u0.z << 16); im[2] = __uint_as_float(u0.z & 0xffff0000u);
  re[3] = __uint_as_float(u0.w << 16); im[3] = __uint_as_float(u0.w & 0xffff0000u);
  re[4] = __uint_as_float(u1.x << 16); im[4] = __uint_as_float(u1.x & 0xffff0000u);
  re[5] = __uint_as_float(u1.y << 16); im[5] = __uint_as_float(u1.y & 0xffff0000u);
  re[6] = __uint_as_float(u1.z << 16); im[6] = __uint_as_float(u1.z & 0xffff0000u);
  re[7] = __uint_as_float(u1.w << 16); im[7] = __uint_as_float(u1.w & 0xffff0000u);
}
__device__ __forceinline__ void load8d(const float* p, float* o) {
  float4 f0 = ((const float4*)p)[0], f1 = ((const float4*)p)[1];
  o[0] = f0.x; o[1] = f0.y; o[2] = f0.z; o[3] = f0.w;
  o[4] = f1.x; o[5] = f1.y; o[6] = f1.z; o[7] = f1.w;
}

// 1000 reduce blocks: one a-row per block, 8 z per thread (8-wide loads,
// 20 independent 32B loads/thread), 1000 block-level atomics.
__global__ __launch_bounds__(256) void k_redprep(
    const unsigned int* __restrict__ Cpk, const float* __restrict__ den,
    float* __restrict__ out, const float* __restrict__ gMN,
    const float* __restrict__ Mm, const bf16* __restrict__ gxHi,
    const bf16* __restrict__ gxLo, const float* __restrict__ Xm,
    unsigned char* __restrict__ B8Next, int ZC, int zg0) {
  __shared__ float sm[64][65];
  const int bid = blockIdx.x, tid = threadIdx.x;
  if (bid >= 1000) {
    int pid = bid - 1000;
    int j0 = (pid & 31) * 64, zl0 = (pid >> 5) * 64;
    int zg0n = zg0 + ZC;
    build_mn(gMN, Mm, B8Next, j0, zl0, zg0n, ZC, tid, sm);
    build_x(gxHi, gxLo, Xm, B8Next, j0, zl0, zg0n, ZC, tid);
    return;
  }
  const size_t PS = (size_t)1024 * ZC;
  const int a = bid;
  float acc = 0.f;
  for (int z = tid * 8; z < ZC; z += 2048) {
    if (zg0 + z >= 2000) break;
    size_t base = (size_t)a * ZC + z;
    float mdr[8], mdi[8], xdr[8], xdi[8], im[8], ix[8];
    load8d(den + 0 * PS + base, mdr);
    load8d(den + 1 * PS + base, mdi);
    load8d(den + 2 * PS + base, xdr);
    load8d(den + 3 * PS + base, xdi);
#pragma unroll
    for (int e = 0; e < 8; ++e) {
      im[e] = 1.f / (mdr[e] * mdr[e] + mdi[e] * mdi[e]);
      ix[e] = 1.f / (xdr[e] * xdr[e] + xdi[e] * xdi[e]);
    }
#pragma unroll
    for (int d = 0; d < 8; ++d) {
      float ar[8], ai[8], br[8], bi[8];
      load8p(Cpk + (size_t)d * PS + base, ar, ai);
      load8p(Cpk + (size_t)(8 + d) * PS + base, br, bi);
#pragma unroll
      for (int e = 0; e < 8; ++e) {
        float r1 = (ar[e] * mdr[e] + ai[e] * mdi[e]) * im[e];
        float i1 = (ai[e] * mdr[e] - ar[e] * mdi[e]) * im[e];
        float r2 = (br[e] * xdr[e] + bi[e] * xdi[e]) * ix[e];
        float i2 = (bi[e] * xdr[e] - br[e] * xdi[e]) * ix[e];
        float dr = r1 - r2, di = i1 - i2;
        acc += dr * dr + di * di;
      }
    }
  }
  for (int off = 32; off; off >>= 1) acc += __shfl_down(acc, off, 64);
  __shared__ float red[4];
  if (!(tid & 63)) red[tid >> 6] = acc;
  __syncthreads();
  if (!tid)
    atomicAdd(out, (red[0] + red[1] + red[2] + red[3]) * (1.f / 2000000.f));
}

// ============================================================================
extern "C" void kernel_launch(void* const* d_in, const int* in_sizes, int n_in,
                              void* d_out, int out_size, void* d_ws,
                              size_t ws_size, hipStream_t stream) {
  const float* Mm  = (const float*)d_in[0];
  const float* Nm  = (const float*)d_in[1];
  const float* Xm  = (const float*)d_in[2];
  const float* ll  = (const float*)d_in[3];
  const float* K11 = (const float*)d_in[4];
  const float* K12 = (const float*)d_in[5];
  const float* gMN = (const float*)d_in[6];
  const float* gN  = (const float*)d_in[7];
  const float* al  = (const float*)d_in[8];

  char* ws = (char*)d_ws;
  const size_t MB = 1024 * 1024;
  bf16* AphH = (bf16*)(ws);                       // 16 MB
  bf16* AphL = (bf16*)(ws + 16 * MB);             // 16 MB
  unsigned char* Aph8 = (unsigned char*)(ws + 32 * MB);  // 8 MB (fp8 phases)
  bf16* gxHi = (bf16*)(ws + 40 * MB);             // 8 MB
  bf16* gxLo = (bf16*)(ws + 48 * MB);             // 8 MB
  bf16* BtNh = (bf16*)(ws + 56 * MB);             // 8 MB
  bf16* BtNl = (bf16*)(ws + 64 * MB);             // 8 MB
  char* chunkRgn = ws + 72 * MB;

  // chunk: B8 16 fp8 planes (32768*ZC) | den (16384*ZC) | Cpk (65536*ZC)
  // transients (Kbf/K12T/K12TL, 24 MB) after the chunk region.
  size_t fixedNeed = 96 * MB;  // 72 fixed + 24 transients
  size_t avail = (ws_size > fixedNeed) ? ws_size - fixedNeed : 0;
  int ZC = 2048;
  while (ZC > 128 && (size_t)114688 * ZC > avail) ZC >>= 1;
  int NC = 2048 / ZC;
  unsigned char* B8c = (unsigned char*)(chunkRgn);
  float* denc = (float*)(chunkRgn + (size_t)32768 * ZC);
  unsigned int* Cpkc = (unsigned int*)(chunkRgn + (size_t)49152 * ZC);
  char* trans = chunkRgn + (size_t)114688 * ZC;
  bf16* Kbf   = (bf16*)(trans);
  bf16* K12T  = (bf16*)(trans + 8 * MB);
  bf16* K12TL = (bf16*)(trans + 16 * MB);

  int NBP = 32 * (ZC / 64);   // prep blocks per chunk
  int GMM = 192 * (ZC >> 7);  // k_mm blocks: num 128*BYT + den 64*BYT

  k_cvt<<<dim3(4096), dim3(256), 0, stream>>>(K11, K12, gN, Kbf, K12T, K12TL,
                                              BtNh, BtNl, (float*)d_out);
  k_big<<<dim3(1280 + NBP), dim3(256), 0, stream>>>(
      K12T, K12TL, Kbf, ll, al, Nm, Xm, gMN, Mm, gxHi, gxLo, AphH, AphL, Aph8,
      B8c, ZC);
  k_prepX<<<dim3(NBP), dim3(256), 0, stream>>>(gxHi, gxLo, Xm, B8c, ZC);
  for (int c = 0; c < NC; ++c) {
    int zg0 = c * ZC;
    k_mm<<<dim3(GMM), dim3(256), 0, stream>>>(
        AphH, AphL, Aph8, B8c, BtNh, BtNl, gxHi, gxLo, Cpkc, denc, ZC, zg0);
    int nblk = (c + 1 < NC) ? 1000 + NBP : 1000;
    k_redprep<<<dim3(nblk), dim3(256), 0, stream>>>(
        Cpkc, denc, (float*)d_out, gMN, Mm, gxHi, gxLo, Xm, B8c, ZC, zg0);
  }
  (void)in_sizes; (void)n_in; (void)out_size;
}

// Round 6
// 448.894 us; speedup vs baseline: 1.2618x; 1.0411x over previous
//
#include <hip/hip_runtime.h>

// ============================================================================
// XModel_66795331387584: complex phase-feature ridge loss on MI355X (gfx950)
//
// loss = mean_{a,z} sum_d | num_MN/den_MN - num_X/den_X |^2
// den path: split-bf16 (hi+lo), fp32 out (tail-dominated 1/|den|^2).
// gamma_X via 1-term Neumann: gx = (K12 - K@K12/reg)/reg (rel err 4e-6).
//
// R10: num GEMM on MX-fp8 (mfma_scale 16x16x128, uniform E8M0 scales).
// R11: T1 XCD map + T2 LDS XOR swizzle + T5 setprio. k_mm 153->118us.
// R12 LESSON: launch_bounds (256,3) VGPR cap 84 -> acc spill (833MB writes).
// R13/R15 LESSON: k_redprep grid: 500-blocks/2-a form is measured-best
//      (457.7); 1000-1a = +10us; 2000-half = +34us. Keep 500.
// R14 LESSON: splitting k_mm phases costs +40us (tails, no co-schedule);
//      but bounded hidden kernels: all <80us.
// R16: k_big gamma_X GEMM 256 blocks(1/CU) -> 512 blocks(2/CU) via 128x64
//      tiles (k_mm den-branch structure). At 1 block/CU the 2-barrier MFMA
//      loop has zero latency hiding once short blocks drain; 2/CU restores
//      wave-level overlap. Epilogue one-pass ft[128][66]. K-order per
//      element unchanged -> bit-identical gx. k_redprep: exact R11 form.
// ============================================================================

typedef __bf16 bf16;
typedef __bf16 bf16x8 __attribute__((ext_vector_type(8)));
typedef float f32x4 __attribute__((ext_vector_type(4)));
typedef int i32x8 __attribute__((ext_vector_type(8)));
typedef int i32x4 __attribute__((ext_vector_type(4)));

#define AS1 __attribute__((address_space(1)))
#define AS3 __attribute__((address_space(3)))

__device__ __forceinline__ void async16(const void* g, void* l) {
  __builtin_amdgcn_global_load_lds((AS1 const unsigned int*)g,
                                   (AS3 unsigned int*)l, 16, 0, 0);
}

__device__ __forceinline__ unsigned int pk4f8(float a, float b, float c,
                                              float d) {
  int w = __builtin_amdgcn_cvt_pk_fp8_f32(a, b, 0, false);
  w = __builtin_amdgcn_cvt_pk_fp8_f32(c, d, w, true);
  return (unsigned int)w;
}

// 32-B fragment read from a 128-B-row LDS tile with 16-B-chunk XOR swizzle.
__device__ __forceinline__ i32x8 ld_swz32(const unsigned char* rowp, int kg,
                                          int fsw) {
  i32x4 lo = *(const i32x4*)(rowp + (kg ^ fsw));
  i32x4 hi = *(const i32x4*)(rowp + ((kg + 16) ^ fsw));
  i32x8 v;
  v[0] = lo[0]; v[1] = lo[1]; v[2] = lo[2]; v[3] = lo[3];
  v[4] = hi[0]; v[5] = hi[1]; v[6] = hi[2]; v[7] = hi[3];
  return v;
}

// Stage a 64x64 f32 tile (row-major src, stride 2000) into LDS t[64][65]
// with float4 loads. 2000%4==0 -> col guard exact at float4 granularity.
__device__ __forceinline__ void stage64x64(const float* __restrict__ src,
                                           int row0, int col0,
                                           float (*t)[65], int tid) {
#pragma unroll
  for (int it = 0; it < 4; ++it) {
    int e = it * 256 + tid;           // 0..1023
    int r = e >> 4, c4 = (e & 15) * 4;
    float4 v = {0.f, 0.f, 0.f, 0.f};
    if (row0 + r < 2000 && col0 + c4 < 2000)
      v = *(const float4*)(src + (size_t)(row0 + r) * 2000 + col0 + c4);
    t[r][c4] = v.x; t[r][c4 + 1] = v.y; t[r][c4 + 2] = v.z; t[r][c4 + 3] = v.w;
  }
}

// -------- B-plane builders (fp8, 64x64 tile) --------------------------------
// planes 0..7: 64 * M_d * gMN^T ; planes 8..15: 8192 * X_d * gx
__device__ __forceinline__ void build_mn(const float* __restrict__ gMN,
                                         const float* __restrict__ Mm,
                                         unsigned char* __restrict__ B8,
                                         int j0, int zl0, int zg0, int ZC,
                                         int tid, float (*t)[65]) {
  const size_t PL = (size_t)ZC * 2048;
  int zg = zg0 + zl0;
  stage64x64(gMN, j0, zg, t, tid);
  __syncthreads();
  const float4* M4 = (const float4*)Mm;
#pragma unroll
  for (int it = 0; it < 2; ++it) {
    int idx = it * 256 + tid;
    int zr = idx >> 3, c8 = (idx & 7) * 8;
    float g[8], mrow[8][8];
#pragma unroll
    for (int e = 0; e < 8; ++e) {
      g[e] = 64.f * t[c8 + e][zr];
      int jj = j0 + c8 + e;
      if (jj < 2000) {
        float4 ma = M4[jj * 2], mb = M4[jj * 2 + 1];
        mrow[e][0] = ma.x; mrow[e][1] = ma.y; mrow[e][2] = ma.z;
        mrow[e][3] = ma.w; mrow[e][4] = mb.x; mrow[e][5] = mb.y;
        mrow[e][6] = mb.z; mrow[e][7] = mb.w;
      } else {
#pragma unroll
        for (int d = 0; d < 8; ++d) mrow[e][d] = 0.f;
      }
    }
    size_t ob = (size_t)(zl0 + zr) * 2048 + j0 + c8;
#pragma unroll
    for (int d = 0; d < 8; ++d) {
      uint2 u;
      u.x = pk4f8(g[0] * mrow[0][d], g[1] * mrow[1][d], g[2] * mrow[2][d],
                  g[3] * mrow[3][d]);
      u.y = pk4f8(g[4] * mrow[4][d], g[5] * mrow[5][d], g[6] * mrow[6][d],
                  g[7] * mrow[7][d]);
      *(uint2*)(B8 + (size_t)d * PL + ob) = u;
    }
  }
}

__device__ __forceinline__ void build_x(const bf16* __restrict__ gxHi,
                                        const bf16* __restrict__ gxLo,
                                        const float* __restrict__ Xm,
                                        unsigned char* __restrict__ B8,
                                        int j0, int zl0, int zg0, int ZC,
                                        int tid) {
  const size_t PL = (size_t)ZC * 2048;
  const float4* X4 = (const float4*)Xm;
#pragma unroll
  for (int it = 0; it < 2; ++it) {
    int idx = it * 256 + tid;
    int zr = idx >> 3, c8 = (idx & 7) * 8;
    size_t gb = (size_t)(zg0 + zl0 + zr) * 2048 + j0 + c8;
    bf16x8 vh = *(const bf16x8*)(gxHi + gb);
    bf16x8 vl = *(const bf16x8*)(gxLo + gb);
    float gx[8], xr[8][8];
#pragma unroll
    for (int e = 0; e < 8; ++e) {
      gx[e] = 8192.f * ((float)vh[e] + (float)vl[e]);
      int jj = j0 + c8 + e;
      if (jj < 2000) {
        float4 xa = X4[jj * 2], xb = X4[jj * 2 + 1];
        xr[e][0] = xa.x; xr[e][1] = xa.y; xr[e][2] = xa.z; xr[e][3] = xa.w;
        xr[e][4] = xb.x; xr[e][5] = xb.y; xr[e][6] = xb.z; xr[e][7] = xb.w;
      } else {
#pragma unroll
        for (int d = 0; d < 8; ++d) xr[e][d] = 0.f;
      }
    }
    size_t ob = (size_t)(zl0 + zr) * 2048 + j0 + c8;
#pragma unroll
    for (int d = 0; d < 8; ++d) {
      uint2 u;
      u.x = pk4f8(gx[0] * xr[0][d], gx[1] * xr[1][d], gx[2] * xr[2][d],
                  gx[3] * xr[3][d]);
      u.y = pk4f8(gx[4] * xr[4][d], gx[5] * xr[5][d], gx[6] * xr[6][d],
                  gx[7] * xr[7][d]);
      *(uint2*)(B8 + (size_t)(8 + d) * PL + ob) = u;
    }
  }
}

// ---------------- k_cvt: converts + gN planes + out zero --------------------
__global__ __launch_bounds__(256) void k_cvt(
    const float* __restrict__ K11, const float* __restrict__ K12,
    const float* __restrict__ gN, bf16* __restrict__ Kbf,
    bf16* __restrict__ K12T, bf16* __restrict__ K12TL,
    bf16* __restrict__ BtNh, bf16* __restrict__ BtNl,
    float* __restrict__ out) {
  __shared__ float t[64][65];
  const int bid = blockIdx.x, tid = threadIdx.x;
  if (bid < 2048) {
    if (bid == 0 && tid == 0) out[0] = 0.f;
    int e = (bid * 256 + tid) * 8;
    int j = e >> 11, k = e & 2047;
    bf16x8 v;
    if (j < 2000 && k < 2000) {
      const float4* s = (const float4*)(K11 + (size_t)j * 2000 + k);
      float4 f0 = s[0], f1 = s[1];
      v[0] = (bf16)f0.x; v[1] = (bf16)f0.y; v[2] = (bf16)f0.z; v[3] = (bf16)f0.w;
      v[4] = (bf16)f1.x; v[5] = (bf16)f1.y; v[6] = (bf16)f1.z; v[7] = (bf16)f1.w;
    } else {
      for (int i = 0; i < 8; ++i) v[i] = (bf16)0.f;
    }
    *(bf16x8*)(Kbf + e) = v;
  } else {
    bool isK12 = bid < 3072;
    const float* src = isK12 ? K12 : gN;
    bf16* dh = isK12 ? K12T : BtNh;
    bf16* dl = isK12 ? K12TL : BtNl;
    int b2 = bid - (isK12 ? 2048 : 3072);
    int j0 = (b2 & 31) * 64, z0 = (b2 >> 5) * 64;
    stage64x64(src, j0, z0, t, tid);
    __syncthreads();
#pragma unroll
    for (int it = 0; it < 2; ++it) {
      int idx = it * 256 + tid;
      int zr = idx >> 3, c8 = (idx & 7) * 8;
      bf16x8 vh, vl;
#pragma unroll
      for (int e = 0; e < 8; ++e) {
        float g = t[c8 + e][zr];
        bf16 h = (bf16)g;
        vh[e] = h;
        vl[e] = (bf16)(g - (float)h);
      }
      size_t ob = (size_t)(z0 + zr) * 2048 + j0 + c8;
      *(bf16x8*)(dh + ob) = vh;
      *(bf16x8*)(dl + ob) = vl;
    }
  }
}

// --------- k_big: gemm1 tiles + phases (+fp8) + prepMN(chunk0) --------------
// R16: gamma_X GEMM now 512 blocks of 128x64 tiles (2 blocks/CU in the tail,
// k_mm den-branch structure). bid<512: GEMM; 512..1535: phases; >=1536: prep.
__global__ __launch_bounds__(256, 2) void k_big(
    const bf16* __restrict__ K12T, const bf16* __restrict__ K12TL,
    const bf16* __restrict__ Kbf, const float* __restrict__ ll,
    const float* __restrict__ al, const float* __restrict__ Nm,
    const float* __restrict__ Xm, const float* __restrict__ gMN,
    const float* __restrict__ Mm, bf16* __restrict__ gxHi,
    bf16* __restrict__ gxLo, bf16* __restrict__ AphH,
    bf16* __restrict__ AphL, unsigned char* __restrict__ Aph8,
    unsigned char* __restrict__ B8, int ZC) {
  __shared__ __align__(16) char smem[34816];
  const int tid = threadIdx.x;
  const int bid = blockIdx.x;
  if (bid >= 1536) {
    int pid = bid - 1536;
    build_mn(gMN, Mm, B8, (pid & 31) * 64, (pid >> 5) * 64, 0, ZC, tid,
             (float(*)[65])smem);
    return;
  }
  if (bid >= 512) {
    // ---- phases: a = bid-512, 8 j per thread
    const size_t PA = (size_t)1024 * 2048;
    int a = bid - 512;
    int j0 = tid * 8;
    float vc[4][8];
    if (a < 1000) {
      const float4* A4 = (const float4*)al;
      const float4* N4 = (const float4*)Nm;
      const float4* X4 = (const float4*)Xm;
      float4 a0 = A4[a * 2], a1 = A4[a * 2 + 1];
#pragma unroll
      for (int e = 0; e < 8; ++e) {
        int j = j0 + e;
        if (j < 2000) {
          float4 n0 = N4[j * 2], n1 = N4[j * 2 + 1];
          float4 x0 = X4[j * 2], x1 = X4[j * 2 + 1];
          float pn = a0.x * n0.x + a0.y * n0.y + a0.z * n0.z + a0.w * n0.w +
                     a1.x * n1.x + a1.y * n1.y + a1.z * n1.z + a1.w * n1.w;
          float px = a0.x * x0.x + a0.y * x0.y + a0.z * x0.z + a0.w * x0.w +
                     a1.x * x1.x + a1.y * x1.y + a1.z * x1.z + a1.w * x1.w;
          __sincosf(pn, &vc[1][e], &vc[0][e]);
          __sincosf(px, &vc[3][e], &vc[2][e]);
        } else {
          vc[0][e] = vc[1][e] = vc[2][e] = vc[3][e] = 0.f;
        }
      }
    } else {
#pragma unroll
      for (int p = 0; p < 4; ++p)
#pragma unroll
        for (int e = 0; e < 8; ++e) vc[p][e] = 0.f;
    }
    size_t o = (size_t)a * 2048 + j0;
#pragma unroll
    for (int p = 0; p < 4; ++p) {
      bf16x8 vh, vl;
#pragma unroll
      for (int e = 0; e < 8; ++e) {
        bf16 h = (bf16)vc[p][e];
        vh[e] = h;
        vl[e] = (bf16)(vc[p][e] - (float)h);
      }
      *(bf16x8*)(AphH + p * PA + o) = vh;
      *(bf16x8*)(AphL + p * PA + o) = vl;
      uint2 u8;
      u8.x = pk4f8(vc[p][0], vc[p][1], vc[p][2], vc[p][3]);
      u8.y = pk4f8(vc[p][4], vc[p][5], vc[p][6], vc[p][7]);
      *(uint2*)(Aph8 + p * PA + o) = u8;
    }
    return;
  }
  // ---- gamma_X tile, 128x64 (T1: xcd=bid&7 owns 2 bm x 32 bn contiguous;
  //      A-panels ~1MB L2-resident per XCD, B streams from LLC)
  bf16(*lds)[64] = (bf16(*)[64])smem;  // A rows 0..127, B rows 128..191
  int wrk = (bid & 7) * 64 + (bid >> 3);
  int bm = (wrk >> 5) * 128;
  int bn = (wrk & 31) * 64;
  const int w = tid >> 6, ln = tid & 63;
  const int fr = ln & 15, kq = (ln >> 4) * 8;
  const int esw = (fr & 7) << 3;  // T2 read-side element XOR
  const int r32 = tid >> 3, c8 = (tid & 7) * 8;
  f32x4 acc[4][2];
#pragma unroll
  for (int i = 0; i < 4; i++)
#pragma unroll
    for (int jj = 0; jj < 2; jj++) acc[i][jj] = {0.f, 0.f, 0.f, 0.f};
  const int m0 = (w & 1) * 64, n0 = (w >> 1) * 32;
  for (int kt = 0; kt < 2048; kt += 64) {
#pragma unroll
    for (int q = 0; q < 4; ++q) {
      int row = q * 32 + r32;
      int sc = c8 ^ ((row & 7) << 3);  // T2 pre-swizzled global source col
      async16(K12T + (size_t)(bm + row) * 2048 + (kt + sc), &lds[row][c8]);
    }
#pragma unroll
    for (int q = 0; q < 2; ++q) {
      int row = q * 32 + r32;
      int sc = c8 ^ ((row & 7) << 3);
      async16(Kbf + (size_t)(bn + row) * 2048 + (kt + sc),
              &lds[128 + row][c8]);
    }
    __syncthreads();
#pragma unroll
    for (int ks = 0; ks < 64; ks += 32) {
      bf16x8 a[4], b[2];
#pragma unroll
      for (int i = 0; i < 4; i++)
        a[i] = *(const bf16x8*)&lds[m0 + i * 16 + fr][(ks + kq) ^ esw];
#pragma unroll
      for (int jj = 0; jj < 2; jj++)
        b[jj] = *(const bf16x8*)&lds[128 + n0 + jj * 16 + fr][(ks + kq) ^ esw];
      __builtin_amdgcn_s_setprio(1);
#pragma unroll
      for (int i = 0; i < 4; i++)
#pragma unroll
        for (int jj = 0; jj < 2; jj++)
          acc[i][jj] = __builtin_amdgcn_mfma_f32_16x16x32_bf16(
              a[i], b[jj], acc[i][jj], 0, 0, 0);
      __builtin_amdgcn_s_setprio(0);
    }
    __syncthreads();
  }
  // ---- epilogue: one-pass ft[128][66] (33792 B), all 4 waves disjoint
  float inv = 1.f / (2000.f * __expf(ll[0]));
  float* ft = (float*)smem;
  const int cr = (ln >> 4) * 4, cc = ln & 15;
#pragma unroll
  for (int i = 0; i < 4; i++)
#pragma unroll
    for (int jj = 0; jj < 2; jj++)
#pragma unroll
      for (int r = 0; r < 4; r++)
        ft[(m0 + i * 16 + cr + r) * 66 + n0 + jj * 16 + cc] = acc[i][jj][r];
  __syncthreads();
#pragma unroll
  for (int it = 0; it < 4; ++it) {
    int idx = it * 256 + tid;
    int m = idx >> 3, cg = (idx & 7) * 8;
    size_t gb = (size_t)(bm + m) * 2048 + bn + cg;
    bf16x8 kh = *(const bf16x8*)(K12T + gb);
    bf16x8 klo = *(const bf16x8*)(K12TL + gb);
    bf16x8 vh, vl;
#pragma unroll
    for (int e = 0; e < 8; ++e) {
      float t1 = ft[m * 66 + cg + e];
      float gx = ((float)kh[e] + (float)klo[e] - t1 * inv) * inv;
      bf16 hh = (bf16)gx;
      vh[e] = hh;
      vl[e] = (bf16)(gx - (float)hh);
    }
    *(bf16x8*)(gxHi + gb) = vh;
    *(bf16x8*)(gxLo + gb) = vl;
  }
}

// ---------------- k_prepX: X planes for chunk 0 -----------------------------
__global__ __launch_bounds__(256) void k_prepX(
    const bf16* __restrict__ gxHi, const bf16* __restrict__ gxLo,
    const float* __restrict__ Xm, unsigned char* __restrict__ B8, int ZC) {
  int pid = blockIdx.x;
  build_x(gxHi, gxLo, Xm, B8, (pid & 31) * 64, (pid >> 5) * 64, 0, ZC,
          threadIdx.x);
}

// --------------------- unified num(fp8)+den(bf16) GEMM ----------------------
// 1-D grid, 192*(ZC/128) blocks. T1 XCD-chunked map: xcd = bid&7 processes
//   slot<16*BYT : num works — zb = xcd*2 + slot/(8*BYT) (XCD owns one cos/sin
//                 A pair, ~4MB, near-L2-resident; 8 bm-blocks per B-tile are
//                 adjacent so each B-tile is fetched into ONE XCD's L2)
//   else        : den works — p = xcd>>1, ny half = xcd&1.
// T2: LDS tiles XOR-swizzled at 16-B-chunk granularity (chunk ^= row&7),
//     applied on the global_load_lds SOURCE address + the LDS read col.
__global__ __launch_bounds__(256, 2) void k_mm(
    const bf16* __restrict__ AphH, const bf16* __restrict__ AphL,
    const unsigned char* __restrict__ Aph8,
    const unsigned char* __restrict__ B8, const bf16* __restrict__ BtNh,
    const bf16* __restrict__ BtNl, const bf16* __restrict__ gxHi,
    const bf16* __restrict__ gxLo, unsigned int* __restrict__ Cpk,
    float* __restrict__ den, int ZC, int zg0) {
  const size_t PA = (size_t)1024 * 2048;
  const size_t PL8 = (size_t)ZC * 2048;  // bytes per fp8 plane
  const size_t PC = (size_t)1024 * ZC;
  __shared__ __align__(16) bf16 smem[3 * 128 * 64];  // 48 KB
  const int tid = threadIdx.x;
  const int w = tid >> 6, ln = tid & 63;
  const int fr = ln & 15;
  const int cr = (ln >> 4) * 4, cc = ln & 15;

  const int BYT = ZC >> 7;        // bn tiles per num plane
  const int nyT = ZC >> 6;        // den ny tiles
  const int xcd = blockIdx.x & 7;
  const int slot = blockIdx.x >> 3;
  const int numSlots = 16 * BYT;  // num works per XCD

  if (slot < numSlots) {
    // ---------------- num pair-plane, fp8 K=128 ----------------
    const int half = numSlots >> 1;  // 8*BYT (pow2)
    int zb = xcd * 2 + (slot >= half ? 1 : 0);
    int rem = slot & (half - 1);
    int bn = (rem >> 3) * 128;
    int bm = (rem & 7) * 128;

    unsigned char* l8 = (unsigned char*)smem;  // 3 planes x [128][128] bytes
    const unsigned char* A0 = Aph8 + (size_t)(zb < 8 ? 0 : 2) * PA;
    const unsigned char* A1 = A0 + PA;
    const unsigned char* B = B8 + (size_t)zb * PL8;
    const int sb = (zb < 8) ? 0x79797979 : 0x72727272;  // 2^-6 / 2^-13
    unsigned int* P = Cpk + (size_t)zb * PC;
    const int colb = (ln & 7) * 16;  // byte col for staging
    const int kg = (ln >> 4) * 32;   // k-byte group for frags
    const int fsw = (fr & 7) << 4;   // T2 read-side byte XOR

    f32x4 acc0[4][4], acc1[4][4];
#pragma unroll
    for (int i = 0; i < 4; i++)
#pragma unroll
      for (int j = 0; j < 4; j++) {
        acc0[i][j] = {0.f, 0.f, 0.f, 0.f};
        acc1[i][j] = {0.f, 0.f, 0.f, 0.f};
      }
    const int m0 = (w & 1) * 64, n0 = (w >> 1) * 64;

    for (int kt = 0; kt < 2048; kt += 128) {
#pragma unroll
      for (int q = 0; q < 4; ++q) {
        int row = w * 32 + q * 8 + (ln >> 3);
        int sc = colb ^ ((row & 7) << 4);  // T2 pre-swizzled source col
        async16(A0 + (size_t)(bm + row) * 2048 + kt + sc,
                l8 + row * 128 + colb);
        async16(A1 + (size_t)(bm + row) * 2048 + kt + sc,
                l8 + 16384 + row * 128 + colb);
        async16(B + (size_t)(bn + row) * 2048 + kt + sc,
                l8 + 32768 + row * 128 + colb);
      }
      __syncthreads();
      i32x8 a0[4], a1[4];
#pragma unroll
      for (int i = 0; i < 4; i++) {
        const unsigned char* pr = l8 + (m0 + i * 16 + fr) * 128;
        a0[i] = ld_swz32(pr, kg, fsw);
        a1[i] = ld_swz32(pr + 16384, kg, fsw);
      }
      __builtin_amdgcn_s_setprio(1);
#pragma unroll
      for (int j = 0; j < 4; ++j) {
        i32x8 bfv =
            ld_swz32(l8 + 32768 + (n0 + j * 16 + fr) * 128, kg, fsw);
#pragma unroll
        for (int i = 0; i < 4; ++i) {
          acc0[i][j] = __builtin_amdgcn_mfma_scale_f32_16x16x128_f8f6f4(
              a0[i], bfv, acc0[i][j], 0, 0, 0, 0x7F7F7F7F, 0, sb);
          acc1[i][j] = __builtin_amdgcn_mfma_scale_f32_16x16x128_f8f6f4(
              a1[i], bfv, acc1[i][j], 0, 0, 0, 0x7F7F7F7F, 0, sb);
        }
      }
      __builtin_amdgcn_s_setprio(0);
      __syncthreads();
    }
#pragma unroll
    for (int i = 0; i < 4; i++)
#pragma unroll
      for (int j = 0; j < 4; j++)
#pragma unroll
        for (int r = 0; r < 4; r++) {
          union { bf16 h[2]; unsigned int u; } pk;
          pk.h[0] = (bf16)acc0[i][j][r];
          pk.h[1] = (bf16)acc1[i][j][r];
          P[(size_t)(bm + m0 + i * 16 + cr + r) * ZC +
            (bn + n0 + j * 16 + cc)] = pk.u;
        }
  } else {
    // ---------------- den tile (split-bf16, 128x64) ----------------
    bf16(*lds)[64] = (bf16(*)[64])smem;
    const int kq = (ln >> 4) * 8;
    const int esw = (fr & 7) << 3;  // T2 read-side element XOR
    int j = slot - numSlots;        // 0 .. 4*nyT-1
    int p = xcd >> 1;
    int ny = (xcd & 1) * (nyT >> 1) + (j >> 3);
    int side = p >> 1, trig = p & 1;
    const bf16* Ah = AphH + (size_t)(side * 2 + trig) * PA;
    const bf16* Al = AphL + (size_t)(side * 2 + trig) * PA;
    const bf16* Bh = (side ? gxHi : BtNh) + (size_t)zg0 * 2048;
    const bf16* Bl = (side ? gxLo : BtNl) + (size_t)zg0 * 2048;
    float* C = den + (size_t)p * PC;
    int bm = (j & 7) * 128, bn = ny * 64;
    const int r32 = tid >> 3, c8 = (tid & 7) * 8;

    f32x4 acc[4][2];
#pragma unroll
    for (int i = 0; i < 4; i++)
#pragma unroll
      for (int jj = 0; jj < 2; jj++) acc[i][jj] = {0.f, 0.f, 0.f, 0.f};
    const int m0 = (w & 1) * 64, n0 = (w >> 1) * 32;

    for (int kt = 0; kt < 2048; kt += 64) {
#pragma unroll
      for (int q = 0; q < 4; ++q) {
        int row = q * 32 + r32;
        int sc = c8 ^ ((row & 7) << 3);
        async16(Ah + (size_t)(bm + row) * 2048 + (kt + sc), &lds[row][c8]);
        async16(Al + (size_t)(bm + row) * 2048 + (kt + sc),
                &lds[128 + row][c8]);
      }
#pragma unroll
      for (int q = 0; q < 2; ++q) {
        int row = q * 32 + r32;
        int sc = c8 ^ ((row & 7) << 3);
        async16(Bh + (size_t)(bn + row) * 2048 + (kt + sc),
                &lds[256 + row][c8]);
        async16(Bl + (size_t)(bn + row) * 2048 + (kt + sc),
                &lds[320 + row][c8]);
      }
      __syncthreads();
#pragma unroll
      for (int ks = 0; ks < 64; ks += 32) {
        bf16x8 ah[4], alo[4], bh[2], blo[2];
#pragma unroll
        for (int i = 0; i < 4; i++) {
          ah[i]  = *(const bf16x8*)&lds[m0 + i * 16 + fr][(ks + kq) ^ esw];
          alo[i] =
              *(const bf16x8*)&lds[128 + m0 + i * 16 + fr][(ks + kq) ^ esw];
        }
#pragma unroll
        for (int jj = 0; jj < 2; jj++) {
          bh[jj] =
              *(const bf16x8*)&lds[256 + n0 + jj * 16 + fr][(ks + kq) ^ esw];
          blo[jj] =
              *(const bf16x8*)&lds[320 + n0 + jj * 16 + fr][(ks + kq) ^ esw];
        }
        __builtin_amdgcn_s_setprio(1);
#pragma unroll
        for (int i = 0; i < 4; i++)
#pragma unroll
          for (int jj = 0; jj < 2; jj++) {
            acc[i][jj] = __builtin_amdgcn_mfma_f32_16x16x32_bf16(
                alo[i], bh[jj], acc[i][jj], 0, 0, 0);
            acc[i][jj] = __builtin_amdgcn_mfma_f32_16x16x32_bf16(
                ah[i], blo[jj], acc[i][jj], 0, 0, 0);
            acc[i][jj] = __builtin_amdgcn_mfma_f32_16x16x32_bf16(
                ah[i], bh[jj], acc[i][jj], 0, 0, 0);
          }
        __builtin_amdgcn_s_setprio(0);
      }
      __syncthreads();
    }
#pragma unroll
    for (int i = 0; i < 4; i++)
#pragma unroll
      for (int jj = 0; jj < 2; jj++)
#pragma unroll
        for (int r = 0; r < 4; r++) {
          size_t idx = (size_t)(bm + m0 + i * 16 + cr + r) * ZC +
                       (bn + n0 + jj * 16 + cc);
          C[idx] = acc[i][jj][r];
        }
  }
}

// ------------- k_redprep: reduce chunk c (+ prep chunk c+1) -----------------
__device__ __forceinline__ void load8p(const unsigned int* p, float* re,
                                       float* im) {
  uint4 u0 = ((const uint4*)p)[0], u1 = ((const uint4*)p)[1];
  re[0] = __uint_as_float(u0.x << 16); im[0] = __uint_as_float(u0.x & 0xffff0000u);
  re[1] = __uint_as_float(u0.y << 16); im[1] = __uint_as_float(u0.y & 0xffff0000u);
  re[2] = __uint_as_float(u0.z << 16); im[2] = __uint_as_float(u0.z & 0xffff0000u);
  re[3] = __uint_as_float(u0.w << 16); im[3] = __uint_as_float(u0.w & 0xffff0000u);
  re[4] = __uint_as_float(u1.x << 16); im[4] = __uint_as_float(u1.x & 0xffff0000u);
  re[5] = __uint_as_float(u1.y << 16); im[5] = __uint_as_float(u1.y & 0xffff0000u);
  re[6] = __uint_as_float(u1.z << 16); im[6] = __uint_as_float(u1.z & 0xffff0000u);
  re[7] = __uint_as_float(u1.w << 16); im[7] = __uint_as_float(u1.w & 0xffff0000u);
}
__device__ __forceinline__ void load8d(const float* p, float* o) {
  float4 f0 = ((const float4*)p)[0], f1 = ((const float4*)p)[1];
  o[0] = f0.x; o[1] = f0.y; o[2] = f0.z; o[3] = f0.w;
  o[4] = f1.x; o[5] = f1.y; o[6] = f1.z; o[7] = f1.w;
}

// R11-exact form (measured best): 500 blocks, 2 a-rows/block (128 thr each),
// 8-wide loads, 500 block-level atomics.
__global__ __launch_bounds__(256) void k_redprep(
    const unsigned int* __restrict__ Cpk, const float* __restrict__ den,
    float* __restrict__ out, const float* __restrict__ gMN,
    const float* __restrict__ Mm, const bf16* __restrict__ gxHi,
    const bf16* __restrict__ gxLo, const float* __restrict__ Xm,
    unsigned char* __restrict__ B8Next, int ZC, int zg0) {
  __shared__ float sm[64][65];
  const int bid = blockIdx.x, tid = threadIdx.x;
  if (bid >= 500) {
    int pid = bid - 500;
    int j0 = (pid & 31) * 64, zl0 = (pid >> 5) * 64;
    int zg0n = zg0 + ZC;
    build_mn(gMN, Mm, B8Next, j0, zl0, zg0n, ZC, tid, sm);
    build_x(gxHi, gxLo, Xm, B8Next, j0, zl0, zg0n, ZC, tid);
    return;
  }
  const size_t PS = (size_t)1024 * ZC;
  int a = bid * 2 + (tid >> 7);
  int zt = tid & 127;
  float acc = 0.f;
  for (int z = zt * 8; z < ZC; z += 1024) {
    if (zg0 + z >= 2000) break;
    size_t base = (size_t)a * ZC + z;
    float mdr[8], mdi[8], xdr[8], xdi[8], im[8], ix[8];
    load8d(den + 0 * PS + base, mdr);
    load8d(den + 1 * PS + base, mdi);
    load8d(den + 2 * PS + base, xdr);
    load8d(den + 3 * PS + base, xdi);
#pragma unroll
    for (int e = 0; e < 8; ++e) {
      im[e] = 1.f / (mdr[e] * mdr[e] + mdi[e] * mdi[e]);
      ix[e] = 1.f / (xdr[e] * xdr[e] + xdi[e] * xdi[e]);
    }
#pragma unroll
    for (int d = 0; d < 8; ++d) {
      float ar[8], ai[8], br[8], bi[8];
      load8p(Cpk + (size_t)d * PS + base, ar, ai);
      load8p(Cpk + (size_t)(8 + d) * PS + base, br, bi);
#pragma unroll
      for (int e = 0; e < 8; ++e) {
        float r1 = (ar[e] * mdr[e] + ai[e] * mdi[e]) * im[e];
        float i1 = (ai[e] * mdr[e] - ar[e] * mdi[e]) * im[e];
        float r2 = (br[e] * xdr[e] + bi[e] * xdi[e]) * ix[e];
        float i2 = (bi[e] * xdr[e] - br[e] * xdi[e]) * ix[e];
        float dr = r1 - r2, di = i1 - i2;
        acc += dr * dr + di * di;
      }
    }
  }
  for (int off = 32; off; off >>= 1) acc += __shfl_down(acc, off, 64);
  __shared__ float red[4];
  if (!(tid & 63)) red[tid >> 6] = acc;
  __syncthreads();
  if (!tid)
    atomicAdd(out, (red[0] + red[1] + red[2] + red[3]) * (1.f / 2000000.f));
}

// ============================================================================
extern "C" void kernel_launch(void* const* d_in, const int* in_sizes, int n_in,
                              void* d_out, int out_size, void* d_ws,
                              size_t ws_size, hipStream_t stream) {
  const float* Mm  = (const float*)d_in[0];
  const float* Nm  = (const float*)d_in[1];
  const float* Xm  = (const float*)d_in[2];
  const float* ll  = (const float*)d_in[3];
  const float* K11 = (const float*)d_in[4];
  const float* K12 = (const float*)d_in[5];
  const float* gMN = (const float*)d_in[6];
  const float* gN  = (const float*)d_in[7];
  const float* al  = (const float*)d_in[8];

  char* ws = (char*)d_ws;
  const size_t MB = 1024 * 1024;
  bf16* AphH = (bf16*)(ws);                       // 16 MB
  bf16* AphL = (bf16*)(ws + 16 * MB);             // 16 MB
  unsigned char* Aph8 = (unsigned char*)(ws + 32 * MB);  // 8 MB (fp8 phases)
  bf16* gxHi = (bf16*)(ws + 40 * MB);             // 8 MB
  bf16* gxLo = (bf16*)(ws + 48 * MB);             // 8 MB
  bf16* BtNh = (bf16*)(ws + 56 * MB);             // 8 MB
  bf16* BtNl = (bf16*)(ws + 64 * MB);             // 8 MB
  char* chunkRgn = ws + 72 * MB;

  // chunk: B8 16 fp8 planes (32768*ZC) | den (16384*ZC) | Cpk (65536*ZC)
  // transients (Kbf/K12T/K12TL, 24 MB) after the chunk region.
  size_t fixedNeed = 96 * MB;  // 72 fixed + 24 transients
  size_t avail = (ws_size > fixedNeed) ? ws_size - fixedNeed : 0;
  int ZC = 2048;
  while (ZC > 128 && (size_t)114688 * ZC > avail) ZC >>= 1;
  int NC = 2048 / ZC;
  unsigned char* B8c = (unsigned char*)(chunkRgn);
  float* denc = (float*)(chunkRgn + (size_t)32768 * ZC);
  unsigned int* Cpkc = (unsigned int*)(chunkRgn + (size_t)49152 * ZC);
  char* trans = chunkRgn + (size_t)114688 * ZC;
  bf16* Kbf   = (bf16*)(trans);
  bf16* K12T  = (bf16*)(trans + 8 * MB);
  bf16* K12TL = (bf16*)(trans + 16 * MB);

  int NBP = 32 * (ZC / 64);   // prep blocks per chunk
  int GMM = 192 * (ZC >> 7);  // k_mm blocks: num 128*BYT + den 64*BYT

  k_cvt<<<dim3(4096), dim3(256), 0, stream>>>(K11, K12, gN, Kbf, K12T, K12TL,
                                              BtNh, BtNl, (float*)d_out);
  k_big<<<dim3(1536 + NBP), dim3(256), 0, stream>>>(
      K12T, K12TL, Kbf, ll, al, Nm, Xm, gMN, Mm, gxHi, gxLo, AphH, AphL, Aph8,
      B8c, ZC);
  k_prepX<<<dim3(NBP), dim3(256), 0, stream>>>(gxHi, gxLo, Xm, B8c, ZC);
  for (int c = 0; c < NC; ++c) {
    int zg0 = c * ZC;
    k_mm<<<dim3(GMM), dim3(256), 0, stream>>>(
        AphH, AphL, Aph8, B8c, BtNh, BtNl, gxHi, gxLo, Cpkc, denc, ZC, zg0);
    int nblk = (c + 1 < NC) ? 500 + NBP : 500;
    k_redprep<<<dim3(nblk), dim3(256), 0, stream>>>(
        Cpkc, denc, (float*)d_out, gMN, Mm, gxHi, gxLo, Xm, B8c, ZC, zg0);
  }
  (void)in_sizes; (void)n_in; (void)out_size;
}